// Round 8
// baseline (284.308 us; speedup 1.0000x reference)
//
#include <hip/hip_runtime.h>
#include <stdint.h>

#define K_TOP 4096
#define CAP 8192            // candidate buffer (pow2, >= K_TOP + ties margin)

// ---- workspace layout (bytes) ----
static constexpr size_t HIST1_OFF = 0;                                   // 4096 u32 = 16 KB
static constexpr size_t HIST2_OFF = 16384;                               // 4096 u32 = 16 KB
static constexpr size_t SCAL_OFF  = 32768;                               // 64 B scalars
static constexpr size_t CAND_OFF  = 32832;                               // CAP u64 = 64 KB
static constexpr size_t TBOX_OFF  = CAND_OFF + (size_t)CAP * 8;          // K float4 = 64 KB
static constexpr size_t TSC_OFF   = TBOX_OFF + (size_t)K_TOP * 16;       // K float = 16 KB
static constexpr size_t MASK_OFF  = TSC_OFF + (size_t)K_TOP * 4;         // K*64 u64 = 2 MB
static constexpr size_t KEEP_OFF  = MASK_OFF + (size_t)K_TOP * 64 * 8;   // 64 u64
static constexpr size_t WS_NEED   = KEEP_OFF + 512;

// scal slots: [0]=B1 [1]=A1(count above B1) [4]=T24 threshold [5]=compact counter

typedef unsigned long long u64;

__device__ __forceinline__ unsigned ord_of(float s) {
    unsigned u = __float_as_uint(s);
    return (u & 0x80000000u) ? ~u : (u | 0x80000000u);
}

__device__ __forceinline__ u64 readlane64(u64 v, int l) {
    unsigned lo = (unsigned)__builtin_amdgcn_readlane((int)(unsigned)v, l);
    unsigned hi = (unsigned)__builtin_amdgcn_readlane((int)(v >> 32), l);
    return ((u64)hi << 32) | lo;
}

// P1: 12-bit histogram (bits 31..20 of ordered score), float4 loads, LDS-privatized
__global__ void k_hist1(const float* __restrict__ scores, unsigned* __restrict__ hist, int n) {
    __shared__ unsigned h[4096];
    for (int j = threadIdx.x; j < 4096; j += 256) h[j] = 0;
    __syncthreads();
    int gid = blockIdx.x * blockDim.x + threadIdx.x;
    int stride = gridDim.x * blockDim.x;
    int n4 = n >> 2;
    const float4* s4 = (const float4*)scores;
    for (int i = gid; i < n4; i += stride) {
        float4 v = s4[i];
        atomicAdd(&h[ord_of(v.x) >> 20], 1u);
        atomicAdd(&h[ord_of(v.y) >> 20], 1u);
        atomicAdd(&h[ord_of(v.z) >> 20], 1u);
        atomicAdd(&h[ord_of(v.w) >> 20], 1u);
    }
    for (int t = (n4 << 2) + gid; t < n; t += stride)
        atomicAdd(&h[ord_of(scores[t]) >> 20], 1u);
    __syncthreads();
    for (int j = threadIdx.x; j < 4096; j += 256) {
        unsigned v = h[j];
        if (v) atomicAdd(&hist[j], v);
    }
}

// P2: 12-bit histogram of bits 19..8 among elements whose top-12 == B1
__global__ void k_hist2(const float* __restrict__ scores, const unsigned* __restrict__ scal,
                        unsigned* __restrict__ hist, int n) {
    __shared__ unsigned h[4096];
    for (int j = threadIdx.x; j < 4096; j += 256) h[j] = 0;
    __syncthreads();
    unsigned B1 = scal[0];
    int gid = blockIdx.x * blockDim.x + threadIdx.x;
    int stride = gridDim.x * blockDim.x;
    int n4 = n >> 2;
    const float4* s4 = (const float4*)scores;
    for (int i = gid; i < n4; i += stride) {
        float4 v = s4[i];
        unsigned o0 = ord_of(v.x), o1 = ord_of(v.y), o2 = ord_of(v.z), o3 = ord_of(v.w);
        if ((o0 >> 20) == B1) atomicAdd(&h[(o0 >> 8) & 4095u], 1u);
        if ((o1 >> 20) == B1) atomicAdd(&h[(o1 >> 8) & 4095u], 1u);
        if ((o2 >> 20) == B1) atomicAdd(&h[(o2 >> 8) & 4095u], 1u);
        if ((o3 >> 20) == B1) atomicAdd(&h[(o3 >> 8) & 4095u], 1u);
    }
    for (int t = (n4 << 2) + gid; t < n; t += stride) {
        unsigned o = ord_of(scores[t]);
        if ((o >> 20) == B1) atomicAdd(&h[(o >> 8) & 4095u], 1u);
    }
    __syncthreads();
    for (int j = threadIdx.x; j < 4096; j += 256) {
        unsigned v = h[j];
        if (v) atomicAdd(&hist[j], v);
    }
}

// select threshold bin from a 4096-bin histogram via suffix scan
__global__ __launch_bounds__(1024) void k_select(const unsigned* __restrict__ hist,
                                                 unsigned* __restrict__ scal, int pass) {
    __shared__ unsigned buf[1024];
    int t = threadIdx.x;
    unsigned c0 = hist[t * 4 + 0], c1 = hist[t * 4 + 1];
    unsigned c2 = hist[t * 4 + 2], c3 = hist[t * 4 + 3];
    unsigned mysum = c0 + c1 + c2 + c3;
    buf[t] = mysum;
    __syncthreads();
    for (int off = 1; off < 1024; off <<= 1) {
        unsigned v = buf[t] + ((t + off < 1024) ? buf[t + off] : 0u);
        __syncthreads();
        buf[t] = v;
        __syncthreads();
    }
    unsigned target = (pass == 0) ? (unsigned)K_TOP : ((unsigned)K_TOP - scal[1]);
    unsigned sfx = buf[t];
    unsigned nxt = (t < 1023) ? buf[t + 1] : 0u;
    if (sfx >= target && nxt < target) {
        unsigned above = nxt;  // count in bins strictly above this 4-bin group
        unsigned b;
        if (above + c3 >= target)                { b = t * 4 + 3; }
        else if (above + c3 + c2 >= target)      { above += c3;           b = t * 4 + 2; }
        else if (above + c3 + c2 + c1 >= target) { above += c3 + c2;      b = t * 4 + 1; }
        else                                     { above += c3 + c2 + c1; b = t * 4 + 0; }
        if (pass == 0) { scal[0] = b; scal[1] = above; }
        else           { scal[4] = (scal[0] << 12) | b; }
    }
}

// compact all elements with 24-bit prefix >= T24, block-aggregated, float4 loads
__global__ __launch_bounds__(256) void k_compact(const float* __restrict__ scores,
                                                 const unsigned* __restrict__ scal,
                                                 u64* __restrict__ cand,
                                                 unsigned* __restrict__ counter, int n) {
    __shared__ unsigned lcount, lbase;
    __shared__ u64 lbuf[4096];
    if (threadIdx.x == 0) lcount = 0;
    __syncthreads();
    unsigned T = scal[4];
    int gid = blockIdx.x * blockDim.x + threadIdx.x;
    int stride = gridDim.x * blockDim.x;
    int n4 = n >> 2;
    const float4* s4 = (const float4*)scores;
    for (int i = gid; i < n4; i += stride) {
        float4 v = s4[i];
        unsigned o0 = ord_of(v.x), o1 = ord_of(v.y), o2 = ord_of(v.z), o3 = ord_of(v.w);
        int base = i << 2;
        if ((o0 >> 8) >= T) lbuf[atomicAdd(&lcount, 1u)] = ((u64)o0 << 32) | (unsigned)(~(base + 0));
        if ((o1 >> 8) >= T) lbuf[atomicAdd(&lcount, 1u)] = ((u64)o1 << 32) | (unsigned)(~(base + 1));
        if ((o2 >> 8) >= T) lbuf[atomicAdd(&lcount, 1u)] = ((u64)o2 << 32) | (unsigned)(~(base + 2));
        if ((o3 >> 8) >= T) lbuf[atomicAdd(&lcount, 1u)] = ((u64)o3 << 32) | (unsigned)(~(base + 3));
    }
    for (int t = (n4 << 2) + gid; t < n; t += stride) {
        unsigned o = ord_of(scores[t]);
        if ((o >> 8) >= T) lbuf[atomicAdd(&lcount, 1u)] = ((u64)o << 32) | (unsigned)(~t);
    }
    __syncthreads();
    if (threadIdx.x == 0) lbase = atomicAdd(counter, lcount);
    __syncthreads();
    for (unsigned j = threadIdx.x; j < lcount; j += 256) {
        unsigned p = lbase + j;
        if (p < CAP) cand[p] = lbuf[j];
    }
}

__device__ __forceinline__ float4 decode_clip(float4 a, float4 d) {
#pragma clang fp contract(off)
    const float BBOX_CLIP = (float)4.135166556742356;  // log(1000/16)
    float w  = a.z - a.x;
    float h  = a.w - a.y;
    float cx = a.x + 0.5f * w;
    float cy = a.y + 0.5f * h;
    float dx = d.x / 10.0f;
    float dy = d.y / 10.0f;
    float dw = fminf(d.z / 5.0f, BBOX_CLIP);
    float dh = fminf(d.w / 5.0f, BBOX_CLIP);
    float pcx = dx * w + cx;
    float pcy = dy * h + cy;
    float pw = (float)exp((double)dw) * w;
    float ph = (float)exp((double)dh) * h;
    float x1 = pcx - 0.5f * pw;
    float y1 = pcy - 0.5f * ph;
    float x2 = pcx + 0.5f * pw;
    float y2 = pcy + 0.5f * ph;
    x1 = fminf(fmaxf(x1, 0.0f), 1333.0f);
    y1 = fminf(fmaxf(y1, 0.0f), 800.0f);
    x2 = fminf(fmaxf(x2, 0.0f), 1333.0f);
    y2 = fminf(fmaxf(y2, 0.0f), 800.0f);
    return make_float4(x1, y1, x2, y2);
}

// rank-by-counting over candidates; decode straight into rank slot.
__global__ __launch_bounds__(256) void k_rank_gather(
        const float* __restrict__ scores, const float* __restrict__ anchors,
        const float* __restrict__ deltas, const u64* __restrict__ cand,
        const unsigned* __restrict__ scal, float4* __restrict__ tbox, float* __restrict__ tsc) {
    __shared__ u64 chunk[256];
    int t = threadIdx.x;
    int j = blockIdx.x * 256 + t;
    unsigned M = scal[5];
    if (M > CAP) M = CAP;
    u64 mykey = (j < (int)M) ? cand[j] : 0ULL;
    unsigned rank = 0;
    for (unsigned base = 0; base < M; base += 256) {
        unsigned idx = base + t;
        chunk[t] = (idx < M) ? cand[idx] : 0ULL;  // pad 0 < any valid key
        __syncthreads();
#pragma unroll 8
        for (int c = 0; c < 256; ++c) rank += (chunk[c] > mykey);
        __syncthreads();
    }
    if (j < (int)M && rank < K_TOP) {
        unsigned idx = ~(unsigned)mykey;
        float4 a = ((const float4*)anchors)[idx];
        float4 d = ((const float4*)deltas)[idx];
        tbox[rank] = decode_clip(a, d);
        tsc[rank]  = scores[idx];
    }
}

// suppression masks. Upper-triangle blocks computed; lower-triangle words
// ZERO-WRITTEN (so the NMS apply phase needs no guard).
__global__ void k_mask(const float4* __restrict__ tbox, u64* __restrict__ mask) {
#pragma clang fp contract(off)
    int w = blockIdx.x;  // column word (64 cols)
    int r = blockIdx.y;  // row block
    int t = threadIdx.x;
    int i = r * 64 + t;
    if (w < r) { mask[(size_t)i * 64 + w] = 0ULL; return; }
    __shared__ float4 cb[64];
    __shared__ float  ca[64];
    float4 b = tbox[w * 64 + t];
    cb[t] = b;
    ca[t] = (b.z - b.x) * (b.w - b.y);
    __syncthreads();
    float4 bi = tbox[i];
    float ai = (bi.z - bi.x) * (bi.w - bi.y);
    u64 bits = 0ULL;
    for (int c = 0; c < 64; ++c) {
        int j = w * 64 + c;
        if (j > i) {
            float4 bj = cb[c];
            float ltx = fmaxf(bi.x, bj.x);
            float lty = fmaxf(bi.y, bj.y);
            float rbx = fminf(bi.z, bj.z);
            float rby = fminf(bi.w, bj.w);
            float ww = fmaxf(rbx - ltx, 0.0f);
            float hh = fmaxf(rby - lty, 0.0f);
            float inter = ww * hh;
            float denom = ((ai + ca[c]) - inter) + 1e-9f;
            float iou = inter / denom;
            if (iou > 0.7f) bits |= (1ULL << c);
        }
    }
    mask[(size_t)i * 64 + w] = bits;
}

// Single-wave greedy NMS. lane l owns column word l.
// Per block: all-64 ds_reads upfront (one lgkm wait), STAGE(b+2),
// then 4 quarters of {32 readlanes -> SGPR diag, 16-step SALU chain},
// then a lean 4-VALU/row apply (uniform SALU masks). The diag tile is
// extracted from the row registers themselves (word b = lane b).
__global__ __launch_bounds__(64, 1) void k_nms(const u64* __restrict__ mask,
                                               u64* __restrict__ keep) {
    __shared__ u64 lbuf[2][64][64];   // 64 KB, double-buffered
    const int lane = threadIdx.x;
    // lane l covers row parity (l>>5), word pair (l&31)*2 of each 1KB sub-load
    const char* gbase = (const char*)mask + ((lane >> 5) << 9) + ((lane & 31) << 4);
    u64 remv = 0ULL;

    // stage block b into lbuf[b&1]: 32 x global_load_lds(16B/lane) = 64 rows
    #define STAGE(b) do {                                                      \
        const char* s_ = gbase + (size_t)(b) * 32768;                          \
        _Pragma("unroll")                                                      \
        for (int j_ = 0; j_ < 32; ++j_)                                        \
            __builtin_amdgcn_global_load_lds(                                  \
                (const unsigned int*)(s_ + j_ * 1024),                         \
                (unsigned int*)&lbuf[(b) & 1][j_ * 2][0], 16, 0, 0);           \
    } while (0)

    // quarter q: scalarize 16 diag words from R, then 16 SALU chain steps
    #define QUARTER(q0) do {                                                   \
        u64 D[16];                                                             \
        _Pragma("unroll")                                                      \
        for (int j_ = 0; j_ < 16; ++j_) D[j_] = readlane64(R[(q0) + j_], b);   \
        _Pragma("unroll")                                                      \
        for (int j_ = 0; j_ < 16; ++j_) {                                      \
            u64 m_ = (u64)0 - ((w >> ((q0) + j_)) & 1ULL);                     \
            w &= ~(D[j_] & m_);                                                \
        }                                                                      \
    } while (0)

    STAGE(0); STAGE(1);

    for (int b = 0; b < 64; ++b) {
        if (b < 63) { asm volatile("s_waitcnt vmcnt(32)" ::: "memory"); }
        else        { asm volatile("s_waitcnt vmcnt(0)"  ::: "memory"); }
        __builtin_amdgcn_sched_barrier(0);

        // all rows of block b -> registers, one wait
        u64 R[64];
        #pragma unroll
        for (int r = 0; r < 64; ++r) R[r] = lbuf[b & 1][r][lane];
        asm volatile("s_waitcnt lgkmcnt(0)" ::: "memory");
        __builtin_amdgcn_sched_barrier(0);
        if (b < 62) STAGE(b + 2);

        // intra-block chain on SALU (w uniform)
        u64 w = ~readlane64(remv, b);
        QUARTER(0); QUARTER(16); QUARTER(32); QUARTER(48);

        // apply kept rows (lower-triangle words are zeroed by k_mask -> no guard)
        #pragma unroll
        for (int r = 0; r < 64; ++r) {
            u64 m = (u64)0 - ((w >> r) & 1ULL);
            remv |= m & R[r];
        }
    }
    keep[lane] = ~remv;

    #undef STAGE
    #undef QUARTER
}

// write [K,5] output
__global__ void k_out(const float4* __restrict__ tbox, const float* __restrict__ tsc,
                      const u64* __restrict__ keep, float* __restrict__ out) {
    int j = blockIdx.x * blockDim.x + threadIdx.x;
    if (j >= K_TOP) return;
    bool kp = (keep[j >> 6] >> (j & 63)) & 1ULL;
    float4 b = tbox[j];
    float sc = tsc[j];
    float* o = out + (size_t)j * 5;
    o[0] = kp ? b.x : 0.0f;
    o[1] = kp ? b.y : 0.0f;
    o[2] = kp ? b.z : 0.0f;
    o[3] = kp ? b.w : 0.0f;
    o[4] = kp ? sc  : 0.0f;
}

extern "C" void kernel_launch(void* const* d_in, const int* in_sizes, int n_in,
                              void* d_out, int out_size, void* d_ws, size_t ws_size,
                              hipStream_t stream) {
    if (ws_size < WS_NEED) return;  // fail loudly (output stays poisoned)
    const float* scores  = (const float*)d_in[0];
    const float* anchors = (const float*)d_in[1];
    const float* deltas  = (const float*)d_in[2];
    int n = in_sizes[0];

    char* ws = (char*)d_ws;
    unsigned* hist1 = (unsigned*)(ws + HIST1_OFF);
    unsigned* hist2 = (unsigned*)(ws + HIST2_OFF);
    unsigned* scal  = (unsigned*)(ws + SCAL_OFF);
    u64* cand       = (u64*)(ws + CAND_OFF);
    float4* tbox    = (float4*)(ws + TBOX_OFF);
    float* tsc      = (float*)(ws + TSC_OFF);
    u64* mask       = (u64*)(ws + MASK_OFF);
    u64* keep       = (u64*)(ws + KEEP_OFF);

    hipMemsetAsync(ws, 0, SCAL_OFF + 64, stream);  // hist1 + hist2 + scalars

    k_hist1<<<256, 256, 0, stream>>>(scores, hist1, n);
    k_select<<<1, 1024, 0, stream>>>(hist1, scal, 0);
    k_hist2<<<256, 256, 0, stream>>>(scores, scal, hist2, n);
    k_select<<<1, 1024, 0, stream>>>(hist2, scal, 1);
    k_compact<<<256, 256, 0, stream>>>(scores, scal, cand, &scal[5], n);
    k_rank_gather<<<CAP / 256, 256, 0, stream>>>(scores, anchors, deltas, cand, scal, tbox, tsc);
    k_mask<<<dim3(64, 64), 64, 0, stream>>>(tbox, mask);
    k_nms<<<1, 64, 0, stream>>>(mask, keep);
    k_out<<<16, 256, 0, stream>>>(tbox, tsc, keep, (float*)d_out);
}

// Round 9
// 243.555 us; speedup vs baseline: 1.1673x; 1.1673x over previous
//
#include <hip/hip_runtime.h>
#include <stdint.h>

#define K_TOP 4096
#define CAP 8192            // candidate buffer (pow2, >= K_TOP + ties margin)

// ---- workspace layout (bytes) ----
static constexpr size_t HIST1_OFF = 0;                                   // 4096 u32 = 16 KB
static constexpr size_t HIST2_OFF = 16384;                               // 4096 u32 = 16 KB
static constexpr size_t SCAL_OFF  = 32768;                               // 64 B scalars
static constexpr size_t CAND_OFF  = 32832;                               // CAP u64 = 64 KB
static constexpr size_t TBOX_OFF  = CAND_OFF + (size_t)CAP * 8;          // K float4 = 64 KB
static constexpr size_t TSC_OFF   = TBOX_OFF + (size_t)K_TOP * 16;       // K float = 16 KB
static constexpr size_t MASK_OFF  = TSC_OFF + (size_t)K_TOP * 4;         // K*64 u64 = 2 MB
static constexpr size_t KEEP_OFF  = MASK_OFF + (size_t)K_TOP * 64 * 8;   // 64 u64
static constexpr size_t WS_NEED   = KEEP_OFF + 512;

// scal slots: [0]=B1 [1]=A1(count above B1) [4]=T24 threshold [5]=compact counter

typedef unsigned long long u64;

__device__ __forceinline__ unsigned ord_of(float s) {
    unsigned u = __float_as_uint(s);
    return (u & 0x80000000u) ? ~u : (u | 0x80000000u);
}

__device__ __forceinline__ u64 readlane64(u64 v, int l) {
    unsigned lo = (unsigned)__builtin_amdgcn_readlane((int)(unsigned)v, l);
    unsigned hi = (unsigned)__builtin_amdgcn_readlane((int)(v >> 32), l);
    return ((u64)hi << 32) | lo;
}

// P1: 12-bit histogram (bits 31..20 of ordered score), float4 loads, LDS-privatized
__global__ void k_hist1(const float* __restrict__ scores, unsigned* __restrict__ hist, int n) {
    __shared__ unsigned h[4096];
    for (int j = threadIdx.x; j < 4096; j += 256) h[j] = 0;
    __syncthreads();
    int gid = blockIdx.x * blockDim.x + threadIdx.x;
    int stride = gridDim.x * blockDim.x;
    int n4 = n >> 2;
    const float4* s4 = (const float4*)scores;
    for (int i = gid; i < n4; i += stride) {
        float4 v = s4[i];
        atomicAdd(&h[ord_of(v.x) >> 20], 1u);
        atomicAdd(&h[ord_of(v.y) >> 20], 1u);
        atomicAdd(&h[ord_of(v.z) >> 20], 1u);
        atomicAdd(&h[ord_of(v.w) >> 20], 1u);
    }
    for (int t = (n4 << 2) + gid; t < n; t += stride)
        atomicAdd(&h[ord_of(scores[t]) >> 20], 1u);
    __syncthreads();
    for (int j = threadIdx.x; j < 4096; j += 256) {
        unsigned v = h[j];
        if (v) atomicAdd(&hist[j], v);
    }
}

// P2: 12-bit histogram of bits 19..8 among elements whose top-12 == B1
__global__ void k_hist2(const float* __restrict__ scores, const unsigned* __restrict__ scal,
                        unsigned* __restrict__ hist, int n) {
    __shared__ unsigned h[4096];
    for (int j = threadIdx.x; j < 4096; j += 256) h[j] = 0;
    __syncthreads();
    unsigned B1 = scal[0];
    int gid = blockIdx.x * blockDim.x + threadIdx.x;
    int stride = gridDim.x * blockDim.x;
    int n4 = n >> 2;
    const float4* s4 = (const float4*)scores;
    for (int i = gid; i < n4; i += stride) {
        float4 v = s4[i];
        unsigned o0 = ord_of(v.x), o1 = ord_of(v.y), o2 = ord_of(v.z), o3 = ord_of(v.w);
        if ((o0 >> 20) == B1) atomicAdd(&h[(o0 >> 8) & 4095u], 1u);
        if ((o1 >> 20) == B1) atomicAdd(&h[(o1 >> 8) & 4095u], 1u);
        if ((o2 >> 20) == B1) atomicAdd(&h[(o2 >> 8) & 4095u], 1u);
        if ((o3 >> 20) == B1) atomicAdd(&h[(o3 >> 8) & 4095u], 1u);
    }
    for (int t = (n4 << 2) + gid; t < n; t += stride) {
        unsigned o = ord_of(scores[t]);
        if ((o >> 20) == B1) atomicAdd(&h[(o >> 8) & 4095u], 1u);
    }
    __syncthreads();
    for (int j = threadIdx.x; j < 4096; j += 256) {
        unsigned v = h[j];
        if (v) atomicAdd(&hist[j], v);
    }
}

// select threshold bin from a 4096-bin histogram via suffix scan
__global__ __launch_bounds__(1024) void k_select(const unsigned* __restrict__ hist,
                                                 unsigned* __restrict__ scal, int pass) {
    __shared__ unsigned buf[1024];
    int t = threadIdx.x;
    unsigned c0 = hist[t * 4 + 0], c1 = hist[t * 4 + 1];
    unsigned c2 = hist[t * 4 + 2], c3 = hist[t * 4 + 3];
    unsigned mysum = c0 + c1 + c2 + c3;
    buf[t] = mysum;
    __syncthreads();
    for (int off = 1; off < 1024; off <<= 1) {
        unsigned v = buf[t] + ((t + off < 1024) ? buf[t + off] : 0u);
        __syncthreads();
        buf[t] = v;
        __syncthreads();
    }
    unsigned target = (pass == 0) ? (unsigned)K_TOP : ((unsigned)K_TOP - scal[1]);
    unsigned sfx = buf[t];
    unsigned nxt = (t < 1023) ? buf[t + 1] : 0u;
    if (sfx >= target && nxt < target) {
        unsigned above = nxt;  // count in bins strictly above this 4-bin group
        unsigned b;
        if (above + c3 >= target)                { b = t * 4 + 3; }
        else if (above + c3 + c2 >= target)      { above += c3;           b = t * 4 + 2; }
        else if (above + c3 + c2 + c1 >= target) { above += c3 + c2;      b = t * 4 + 1; }
        else                                     { above += c3 + c2 + c1; b = t * 4 + 0; }
        if (pass == 0) { scal[0] = b; scal[1] = above; }
        else           { scal[4] = (scal[0] << 12) | b; }
    }
}

// compact all elements with 24-bit prefix >= T24, block-aggregated, float4 loads
__global__ __launch_bounds__(256) void k_compact(const float* __restrict__ scores,
                                                 const unsigned* __restrict__ scal,
                                                 u64* __restrict__ cand,
                                                 unsigned* __restrict__ counter, int n) {
    __shared__ unsigned lcount, lbase;
    __shared__ u64 lbuf[4096];
    if (threadIdx.x == 0) lcount = 0;
    __syncthreads();
    unsigned T = scal[4];
    int gid = blockIdx.x * blockDim.x + threadIdx.x;
    int stride = gridDim.x * blockDim.x;
    int n4 = n >> 2;
    const float4* s4 = (const float4*)scores;
    for (int i = gid; i < n4; i += stride) {
        float4 v = s4[i];
        unsigned o0 = ord_of(v.x), o1 = ord_of(v.y), o2 = ord_of(v.z), o3 = ord_of(v.w);
        int base = i << 2;
        if ((o0 >> 8) >= T) lbuf[atomicAdd(&lcount, 1u)] = ((u64)o0 << 32) | (unsigned)(~(base + 0));
        if ((o1 >> 8) >= T) lbuf[atomicAdd(&lcount, 1u)] = ((u64)o1 << 32) | (unsigned)(~(base + 1));
        if ((o2 >> 8) >= T) lbuf[atomicAdd(&lcount, 1u)] = ((u64)o2 << 32) | (unsigned)(~(base + 2));
        if ((o3 >> 8) >= T) lbuf[atomicAdd(&lcount, 1u)] = ((u64)o3 << 32) | (unsigned)(~(base + 3));
    }
    for (int t = (n4 << 2) + gid; t < n; t += stride) {
        unsigned o = ord_of(scores[t]);
        if ((o >> 8) >= T) lbuf[atomicAdd(&lcount, 1u)] = ((u64)o << 32) | (unsigned)(~t);
    }
    __syncthreads();
    if (threadIdx.x == 0) lbase = atomicAdd(counter, lcount);
    __syncthreads();
    for (unsigned j = threadIdx.x; j < lcount; j += 256) {
        unsigned p = lbase + j;
        if (p < CAP) cand[p] = lbuf[j];
    }
}

__device__ __forceinline__ float4 decode_clip(float4 a, float4 d) {
#pragma clang fp contract(off)
    const float BBOX_CLIP = (float)4.135166556742356;  // log(1000/16)
    float w  = a.z - a.x;
    float h  = a.w - a.y;
    float cx = a.x + 0.5f * w;
    float cy = a.y + 0.5f * h;
    float dx = d.x / 10.0f;
    float dy = d.y / 10.0f;
    float dw = fminf(d.z / 5.0f, BBOX_CLIP);
    float dh = fminf(d.w / 5.0f, BBOX_CLIP);
    float pcx = dx * w + cx;
    float pcy = dy * h + cy;
    float pw = (float)exp((double)dw) * w;
    float ph = (float)exp((double)dh) * h;
    float x1 = pcx - 0.5f * pw;
    float y1 = pcy - 0.5f * ph;
    float x2 = pcx + 0.5f * pw;
    float y2 = pcy + 0.5f * ph;
    x1 = fminf(fmaxf(x1, 0.0f), 1333.0f);
    y1 = fminf(fmaxf(y1, 0.0f), 800.0f);
    x2 = fminf(fmaxf(x2, 0.0f), 1333.0f);
    y2 = fminf(fmaxf(y2, 0.0f), 800.0f);
    return make_float4(x1, y1, x2, y2);
}

// rank-by-counting over candidates; decode straight into rank slot.
__global__ __launch_bounds__(256) void k_rank_gather(
        const float* __restrict__ scores, const float* __restrict__ anchors,
        const float* __restrict__ deltas, const u64* __restrict__ cand,
        const unsigned* __restrict__ scal, float4* __restrict__ tbox, float* __restrict__ tsc) {
    __shared__ u64 chunk[256];
    int t = threadIdx.x;
    int j = blockIdx.x * 256 + t;
    unsigned M = scal[5];
    if (M > CAP) M = CAP;
    u64 mykey = (j < (int)M) ? cand[j] : 0ULL;
    unsigned rank = 0;
    for (unsigned base = 0; base < M; base += 256) {
        unsigned idx = base + t;
        chunk[t] = (idx < M) ? cand[idx] : 0ULL;  // pad 0 < any valid key
        __syncthreads();
#pragma unroll 8
        for (int c = 0; c < 256; ++c) rank += (chunk[c] > mykey);
        __syncthreads();
    }
    if (j < (int)M && rank < K_TOP) {
        unsigned idx = ~(unsigned)mykey;
        float4 a = ((const float4*)anchors)[idx];
        float4 d = ((const float4*)deltas)[idx];
        tbox[rank] = decode_clip(a, d);
        tsc[rank]  = scores[idx];
    }
}

// suppression masks. Upper-triangle blocks computed; lower-triangle words
// ZERO-WRITTEN (so the NMS apply phase needs no guard).
__global__ void k_mask(const float4* __restrict__ tbox, u64* __restrict__ mask) {
#pragma clang fp contract(off)
    int w = blockIdx.x;  // column word (64 cols)
    int r = blockIdx.y;  // row block
    int t = threadIdx.x;
    int i = r * 64 + t;
    if (w < r) { mask[(size_t)i * 64 + w] = 0ULL; return; }
    __shared__ float4 cb[64];
    __shared__ float  ca[64];
    float4 b = tbox[w * 64 + t];
    cb[t] = b;
    ca[t] = (b.z - b.x) * (b.w - b.y);
    __syncthreads();
    float4 bi = tbox[i];
    float ai = (bi.z - bi.x) * (bi.w - bi.y);
    u64 bits = 0ULL;
    for (int c = 0; c < 64; ++c) {
        int j = w * 64 + c;
        if (j > i) {
            float4 bj = cb[c];
            float ltx = fmaxf(bi.x, bj.x);
            float lty = fmaxf(bi.y, bj.y);
            float rbx = fminf(bi.z, bj.z);
            float rby = fminf(bi.w, bj.w);
            float ww = fmaxf(rbx - ltx, 0.0f);
            float hh = fmaxf(rby - lty, 0.0f);
            float inter = ww * hh;
            float denom = ((ai + ca[c]) - inter) + 1e-9f;
            float iou = inter / denom;
            if (iou > 0.7f) bits |= (1ULL << c);
        }
    }
    mask[(size_t)i * 64 + w] = bits;
}

// 4-wave greedy NMS (256 threads, one wave per SIMD). lane l owns column
// word l; wave v owns rows v*16..v*16+15 of every 64-row block.
// Per wave per block: 8 global_load_lds (own 16 rows) + 1 asm global diag
// load = 9 VMEM ops -> exact per-wave counted vmcnt(9). The 64-step serial
// chain runs redundantly in all 4 waves (parallel across SIMDs, no
// broadcast needed). One raw s_barrier per block orders the 4xu64 partial-
// remv publish (parity double-buffered). lgkm-only drains; staged loads
// stay in flight across barriers.
__global__ __launch_bounds__(256, 1) void k_nms(const u64* __restrict__ mask,
                                                u64* __restrict__ keep) {
    __shared__ u64 lbuf[2][64][64];   // 64 KB, double-buffered
    __shared__ u64 s_part[2][4];
    __shared__ u64 s_all[4][64];
    const int lane = threadIdx.x & 63;
    const int wv   = threadIdx.x >> 6;
    u64 remv = 0ULL;
    u64 dA, dB;

    // stage wave wv's 16 rows of block b (8 KB = 8 x 1KB loads)
    #define STAGE(b, PAR) do {                                                 \
        const char* s_ = (const char*)mask + (size_t)(b) * 32768 + wv * 8192   \
                         + ((lane >> 5) << 9) + ((lane & 31) << 4);            \
        _Pragma("unroll")                                                      \
        for (int j_ = 0; j_ < 8; ++j_)                                         \
            __builtin_amdgcn_global_load_lds(                                  \
                (const unsigned int*)(s_ + j_ * 1024),                         \
                (unsigned int*)&lbuf[PAR][wv * 16 + j_ * 2][0], 16, 0, 0);     \
    } while (0)

    // per-lane diag word: lane r holds word b of row b*64+r (asm: issue-pinned)
    #define DIAG(b, dreg) do {                                                 \
        const u64* p_ = mask + (((size_t)((b) * 64 + lane)) << 6) + (b);       \
        asm volatile("global_load_dwordx2 %0, %1, off" : "=&v"(dreg) : "v"(p_)); \
    } while (0)

    #define BLOCK(b, PAR, dcur) do {                                           \
        if ((b) < 63) { asm volatile("s_waitcnt vmcnt(9)" ::: "memory"); }     \
        else          { asm volatile("s_waitcnt vmcnt(0)" ::: "memory"); }     \
        __builtin_amdgcn_sched_barrier(0);                                     \
        __builtin_amdgcn_s_barrier();                                          \
        __builtin_amdgcn_sched_barrier(0);                                     \
        u64 p0 = s_part[PAR][0], p1 = s_part[PAR][1];                          \
        u64 p2 = s_part[PAR][2], p3 = s_part[PAR][3];                          \
        u64 R[16];                                                             \
        _Pragma("unroll")                                                      \
        for (int j_ = 0; j_ < 16; ++j_) R[j_] = lbuf[PAR][wv * 16 + j_][lane]; \
        if ((b) < 62) STAGE((b) + 2, PAR);                                     \
        asm volatile("s_waitcnt lgkmcnt(0)" ::: "memory");                     \
        __builtin_amdgcn_sched_barrier(0);                                     \
        u64 w = ~(p0 | p1 | p2 | p3);                                          \
        _Pragma("unroll")                                                      \
        for (int q_ = 0; q_ < 4; ++q_) {                                       \
            u64 D[16];                                                         \
            _Pragma("unroll")                                                  \
            for (int j_ = 0; j_ < 16; ++j_) D[j_] = readlane64(dcur, q_ * 16 + j_); \
            _Pragma("unroll")                                                  \
            for (int j_ = 0; j_ < 16; ++j_) {                                  \
                u64 m_ = (u64)0 - ((w >> (q_ * 16 + j_)) & 1ULL);              \
                w &= ~(D[j_] & m_);                                            \
            }                                                                  \
        }                                                                      \
        _Pragma("unroll")                                                      \
        for (int j_ = 0; j_ < 16; ++j_) {                                      \
            u64 m_ = (u64)0 - ((w >> (wv * 16 + j_)) & 1ULL);                  \
            remv |= m_ & R[j_];                                                \
        }                                                                      \
        if ((b) < 63) {                                                        \
            u64 pub = readlane64(remv, (b) + 1);                               \
            if (lane == 0) s_part[PAR ^ 1][wv] = pub;                          \
        }                                                                      \
        if ((b) < 62) DIAG((b) + 2, dcur);                                     \
        asm volatile("s_waitcnt lgkmcnt(0)" ::: "memory");                     \
        __builtin_amdgcn_sched_barrier(0);                                     \
    } while (0)

    // prologue: zero block-0 publish slot; blocks 0 and 1 fully in flight
    if (lane == 0) s_part[0][wv] = 0ULL;
    STAGE(0, 0); DIAG(0, dA);
    STAGE(1, 1); DIAG(1, dB);

    for (int bb = 0; bb < 32; ++bb) {
        int b = bb * 2;
        BLOCK(b,     0, dA);
        BLOCK(b + 1, 1, dB);
    }
    #undef STAGE
    #undef DIAG
    #undef BLOCK

    s_all[wv][lane] = remv;
    __syncthreads();
    if (wv == 0)
        keep[lane] = ~(s_all[0][lane] | s_all[1][lane] | s_all[2][lane] | s_all[3][lane]);
}

// write [K,5] output
__global__ void k_out(const float4* __restrict__ tbox, const float* __restrict__ tsc,
                      const u64* __restrict__ keep, float* __restrict__ out) {
    int j = blockIdx.x * blockDim.x + threadIdx.x;
    if (j >= K_TOP) return;
    bool kp = (keep[j >> 6] >> (j & 63)) & 1ULL;
    float4 b = tbox[j];
    float sc = tsc[j];
    float* o = out + (size_t)j * 5;
    o[0] = kp ? b.x : 0.0f;
    o[1] = kp ? b.y : 0.0f;
    o[2] = kp ? b.z : 0.0f;
    o[3] = kp ? b.w : 0.0f;
    o[4] = kp ? sc  : 0.0f;
}

extern "C" void kernel_launch(void* const* d_in, const int* in_sizes, int n_in,
                              void* d_out, int out_size, void* d_ws, size_t ws_size,
                              hipStream_t stream) {
    if (ws_size < WS_NEED) return;  // fail loudly (output stays poisoned)
    const float* scores  = (const float*)d_in[0];
    const float* anchors = (const float*)d_in[1];
    const float* deltas  = (const float*)d_in[2];
    int n = in_sizes[0];

    char* ws = (char*)d_ws;
    unsigned* hist1 = (unsigned*)(ws + HIST1_OFF);
    unsigned* hist2 = (unsigned*)(ws + HIST2_OFF);
    unsigned* scal  = (unsigned*)(ws + SCAL_OFF);
    u64* cand       = (u64*)(ws + CAND_OFF);
    float4* tbox    = (float4*)(ws + TBOX_OFF);
    float* tsc      = (float*)(ws + TSC_OFF);
    u64* mask       = (u64*)(ws + MASK_OFF);
    u64* keep       = (u64*)(ws + KEEP_OFF);

    hipMemsetAsync(ws, 0, SCAL_OFF + 64, stream);  // hist1 + hist2 + scalars

    k_hist1<<<256, 256, 0, stream>>>(scores, hist1, n);
    k_select<<<1, 1024, 0, stream>>>(hist1, scal, 0);
    k_hist2<<<256, 256, 0, stream>>>(scores, scal, hist2, n);
    k_select<<<1, 1024, 0, stream>>>(hist2, scal, 1);
    k_compact<<<256, 256, 0, stream>>>(scores, scal, cand, &scal[5], n);
    k_rank_gather<<<CAP / 256, 256, 0, stream>>>(scores, anchors, deltas, cand, scal, tbox, tsc);
    k_mask<<<dim3(64, 64), 64, 0, stream>>>(tbox, mask);
    k_nms<<<1, 256, 0, stream>>>(mask, keep);
    k_out<<<16, 256, 0, stream>>>(tbox, tsc, keep, (float*)d_out);
}

// Round 10
// 216.152 us; speedup vs baseline: 1.3153x; 1.1268x over previous
//
#include <hip/hip_runtime.h>
#include <stdint.h>

#define K_TOP 4096
#define CAP 8192            // candidate buffer (pow2, >= K_TOP + ties margin)

// ---- workspace layout (bytes) ----
static constexpr size_t HIST1_OFF = 0;                                   // 4096 u32 = 16 KB
static constexpr size_t HIST2_OFF = 16384;                               // 4096 u32 = 16 KB
static constexpr size_t SCAL_OFF  = 32768;                               // 64 B scalars
static constexpr size_t CAND_OFF  = 32832;                               // CAP u64 = 64 KB
static constexpr size_t TBOX_OFF  = CAND_OFF + (size_t)CAP * 8;          // K float4 = 64 KB
static constexpr size_t TSC_OFF   = TBOX_OFF + (size_t)K_TOP * 16;       // K float = 16 KB
static constexpr size_t MASK_OFF  = TSC_OFF + (size_t)K_TOP * 4;         // K*64 u64 = 2 MB
static constexpr size_t KEEP_OFF  = MASK_OFF + (size_t)K_TOP * 64 * 8;   // 64 u64
static constexpr size_t WS_NEED   = KEEP_OFF + 512;

// scal slots: [0]=B1 [1]=A1(count above B1) [4]=T24 threshold [5]=compact counter

typedef unsigned long long u64;

__device__ __forceinline__ unsigned ord_of(float s) {
    unsigned u = __float_as_uint(s);
    return (u & 0x80000000u) ? ~u : (u | 0x80000000u);
}

__device__ __forceinline__ u64 readlane64(u64 v, int l) {
    unsigned lo = (unsigned)__builtin_amdgcn_readlane((int)(unsigned)v, l);
    unsigned hi = (unsigned)__builtin_amdgcn_readlane((int)(v >> 32), l);
    return ((u64)hi << 32) | lo;
}

__device__ __forceinline__ u64 readfirstlane64(u64 v) {
    unsigned lo = (unsigned)__builtin_amdgcn_readfirstlane((int)(unsigned)v);
    unsigned hi = (unsigned)__builtin_amdgcn_readfirstlane((int)(v >> 32));
    return ((u64)hi << 32) | lo;
}

// P1: 12-bit histogram (bits 31..20 of ordered score), float4 loads, LDS-privatized
__global__ void k_hist1(const float* __restrict__ scores, unsigned* __restrict__ hist, int n) {
    __shared__ unsigned h[4096];
    for (int j = threadIdx.x; j < 4096; j += 256) h[j] = 0;
    __syncthreads();
    int gid = blockIdx.x * blockDim.x + threadIdx.x;
    int stride = gridDim.x * blockDim.x;
    int n4 = n >> 2;
    const float4* s4 = (const float4*)scores;
    for (int i = gid; i < n4; i += stride) {
        float4 v = s4[i];
        atomicAdd(&h[ord_of(v.x) >> 20], 1u);
        atomicAdd(&h[ord_of(v.y) >> 20], 1u);
        atomicAdd(&h[ord_of(v.z) >> 20], 1u);
        atomicAdd(&h[ord_of(v.w) >> 20], 1u);
    }
    for (int t = (n4 << 2) + gid; t < n; t += stride)
        atomicAdd(&h[ord_of(scores[t]) >> 20], 1u);
    __syncthreads();
    for (int j = threadIdx.x; j < 4096; j += 256) {
        unsigned v = h[j];
        if (v) atomicAdd(&hist[j], v);
    }
}

// P2: 12-bit histogram of bits 19..8 among elements whose top-12 == B1
__global__ void k_hist2(const float* __restrict__ scores, const unsigned* __restrict__ scal,
                        unsigned* __restrict__ hist, int n) {
    __shared__ unsigned h[4096];
    for (int j = threadIdx.x; j < 4096; j += 256) h[j] = 0;
    __syncthreads();
    unsigned B1 = scal[0];
    int gid = blockIdx.x * blockDim.x + threadIdx.x;
    int stride = gridDim.x * blockDim.x;
    int n4 = n >> 2;
    const float4* s4 = (const float4*)scores;
    for (int i = gid; i < n4; i += stride) {
        float4 v = s4[i];
        unsigned o0 = ord_of(v.x), o1 = ord_of(v.y), o2 = ord_of(v.z), o3 = ord_of(v.w);
        if ((o0 >> 20) == B1) atomicAdd(&h[(o0 >> 8) & 4095u], 1u);
        if ((o1 >> 20) == B1) atomicAdd(&h[(o1 >> 8) & 4095u], 1u);
        if ((o2 >> 20) == B1) atomicAdd(&h[(o2 >> 8) & 4095u], 1u);
        if ((o3 >> 20) == B1) atomicAdd(&h[(o3 >> 8) & 4095u], 1u);
    }
    for (int t = (n4 << 2) + gid; t < n; t += stride) {
        unsigned o = ord_of(scores[t]);
        if ((o >> 20) == B1) atomicAdd(&h[(o >> 8) & 4095u], 1u);
    }
    __syncthreads();
    for (int j = threadIdx.x; j < 4096; j += 256) {
        unsigned v = h[j];
        if (v) atomicAdd(&hist[j], v);
    }
}

// select threshold bin from a 4096-bin histogram via suffix scan
__global__ __launch_bounds__(1024) void k_select(const unsigned* __restrict__ hist,
                                                 unsigned* __restrict__ scal, int pass) {
    __shared__ unsigned buf[1024];
    int t = threadIdx.x;
    unsigned c0 = hist[t * 4 + 0], c1 = hist[t * 4 + 1];
    unsigned c2 = hist[t * 4 + 2], c3 = hist[t * 4 + 3];
    unsigned mysum = c0 + c1 + c2 + c3;
    buf[t] = mysum;
    __syncthreads();
    for (int off = 1; off < 1024; off <<= 1) {
        unsigned v = buf[t] + ((t + off < 1024) ? buf[t + off] : 0u);
        __syncthreads();
        buf[t] = v;
        __syncthreads();
    }
    unsigned target = (pass == 0) ? (unsigned)K_TOP : ((unsigned)K_TOP - scal[1]);
    unsigned sfx = buf[t];
    unsigned nxt = (t < 1023) ? buf[t + 1] : 0u;
    if (sfx >= target && nxt < target) {
        unsigned above = nxt;  // count in bins strictly above this 4-bin group
        unsigned b;
        if (above + c3 >= target)                { b = t * 4 + 3; }
        else if (above + c3 + c2 >= target)      { above += c3;           b = t * 4 + 2; }
        else if (above + c3 + c2 + c1 >= target) { above += c3 + c2;      b = t * 4 + 1; }
        else                                     { above += c3 + c2 + c1; b = t * 4 + 0; }
        if (pass == 0) { scal[0] = b; scal[1] = above; }
        else           { scal[4] = (scal[0] << 12) | b; }
    }
}

// compact all elements with 24-bit prefix >= T24, block-aggregated, float4 loads
__global__ __launch_bounds__(256) void k_compact(const float* __restrict__ scores,
                                                 const unsigned* __restrict__ scal,
                                                 u64* __restrict__ cand,
                                                 unsigned* __restrict__ counter, int n) {
    __shared__ unsigned lcount, lbase;
    __shared__ u64 lbuf[4096];
    if (threadIdx.x == 0) lcount = 0;
    __syncthreads();
    unsigned T = scal[4];
    int gid = blockIdx.x * blockDim.x + threadIdx.x;
    int stride = gridDim.x * blockDim.x;
    int n4 = n >> 2;
    const float4* s4 = (const float4*)scores;
    for (int i = gid; i < n4; i += stride) {
        float4 v = s4[i];
        unsigned o0 = ord_of(v.x), o1 = ord_of(v.y), o2 = ord_of(v.z), o3 = ord_of(v.w);
        int base = i << 2;
        if ((o0 >> 8) >= T) lbuf[atomicAdd(&lcount, 1u)] = ((u64)o0 << 32) | (unsigned)(~(base + 0));
        if ((o1 >> 8) >= T) lbuf[atomicAdd(&lcount, 1u)] = ((u64)o1 << 32) | (unsigned)(~(base + 1));
        if ((o2 >> 8) >= T) lbuf[atomicAdd(&lcount, 1u)] = ((u64)o2 << 32) | (unsigned)(~(base + 2));
        if ((o3 >> 8) >= T) lbuf[atomicAdd(&lcount, 1u)] = ((u64)o3 << 32) | (unsigned)(~(base + 3));
    }
    for (int t = (n4 << 2) + gid; t < n; t += stride) {
        unsigned o = ord_of(scores[t]);
        if ((o >> 8) >= T) lbuf[atomicAdd(&lcount, 1u)] = ((u64)o << 32) | (unsigned)(~t);
    }
    __syncthreads();
    if (threadIdx.x == 0) lbase = atomicAdd(counter, lcount);
    __syncthreads();
    for (unsigned j = threadIdx.x; j < lcount; j += 256) {
        unsigned p = lbase + j;
        if (p < CAP) cand[p] = lbuf[j];
    }
}

__device__ __forceinline__ float4 decode_clip(float4 a, float4 d) {
#pragma clang fp contract(off)
    const float BBOX_CLIP = (float)4.135166556742356;  // log(1000/16)
    float w  = a.z - a.x;
    float h  = a.w - a.y;
    float cx = a.x + 0.5f * w;
    float cy = a.y + 0.5f * h;
    float dx = d.x / 10.0f;
    float dy = d.y / 10.0f;
    float dw = fminf(d.z / 5.0f, BBOX_CLIP);
    float dh = fminf(d.w / 5.0f, BBOX_CLIP);
    float pcx = dx * w + cx;
    float pcy = dy * h + cy;
    float pw = (float)exp((double)dw) * w;
    float ph = (float)exp((double)dh) * h;
    float x1 = pcx - 0.5f * pw;
    float y1 = pcy - 0.5f * ph;
    float x2 = pcx + 0.5f * pw;
    float y2 = pcy + 0.5f * ph;
    x1 = fminf(fmaxf(x1, 0.0f), 1333.0f);
    y1 = fminf(fmaxf(y1, 0.0f), 800.0f);
    x2 = fminf(fmaxf(x2, 0.0f), 1333.0f);
    y2 = fminf(fmaxf(y2, 0.0f), 800.0f);
    return make_float4(x1, y1, x2, y2);
}

// rank-by-counting over candidates; decode straight into rank slot.
__global__ __launch_bounds__(256) void k_rank_gather(
        const float* __restrict__ scores, const float* __restrict__ anchors,
        const float* __restrict__ deltas, const u64* __restrict__ cand,
        const unsigned* __restrict__ scal, float4* __restrict__ tbox, float* __restrict__ tsc) {
    __shared__ u64 chunk[256];
    int t = threadIdx.x;
    int j = blockIdx.x * 256 + t;
    unsigned M = scal[5];
    if (M > CAP) M = CAP;
    u64 mykey = (j < (int)M) ? cand[j] : 0ULL;
    unsigned rank = 0;
    for (unsigned base = 0; base < M; base += 256) {
        unsigned idx = base + t;
        chunk[t] = (idx < M) ? cand[idx] : 0ULL;  // pad 0 < any valid key
        __syncthreads();
#pragma unroll 8
        for (int c = 0; c < 256; ++c) rank += (chunk[c] > mykey);
        __syncthreads();
    }
    if (j < (int)M && rank < K_TOP) {
        unsigned idx = ~(unsigned)mykey;
        float4 a = ((const float4*)anchors)[idx];
        float4 d = ((const float4*)deltas)[idx];
        tbox[rank] = decode_clip(a, d);
        tsc[rank]  = scores[idx];
    }
}

// suppression masks. Upper-triangle blocks computed; lower-triangle words
// ZERO-WRITTEN (so the NMS apply phase needs no guard).
__global__ void k_mask(const float4* __restrict__ tbox, u64* __restrict__ mask) {
#pragma clang fp contract(off)
    int w = blockIdx.x;  // column word (64 cols)
    int r = blockIdx.y;  // row block
    int t = threadIdx.x;
    int i = r * 64 + t;
    if (w < r) { mask[(size_t)i * 64 + w] = 0ULL; return; }
    __shared__ float4 cb[64];
    __shared__ float  ca[64];
    float4 b = tbox[w * 64 + t];
    cb[t] = b;
    ca[t] = (b.z - b.x) * (b.w - b.y);
    __syncthreads();
    float4 bi = tbox[i];
    float ai = (bi.z - bi.x) * (bi.w - bi.y);
    u64 bits = 0ULL;
    for (int c = 0; c < 64; ++c) {
        int j = w * 64 + c;
        if (j > i) {
            float4 bj = cb[c];
            float ltx = fmaxf(bi.x, bj.x);
            float lty = fmaxf(bi.y, bj.y);
            float rbx = fminf(bi.z, bj.z);
            float rby = fminf(bi.w, bj.w);
            float ww = fmaxf(rbx - ltx, 0.0f);
            float hh = fmaxf(rby - lty, 0.0f);
            float inter = ww * hh;
            float denom = ((ai + ca[c]) - inter) + 1e-9f;
            float iou = inter / denom;
            if (iou > 0.7f) bits |= (1ULL << c);
        }
    }
    mask[(size_t)i * 64 + w] = bits;
}

// 4-wave greedy NMS (256 threads). lane l owns column word l; wave v owns
// rows v*16..+15 of each 64-row block. Staging: 8 global_load_lds + 1 asm
// diag load per wave per block = 9 VMEM -> exact counted vmcnt(9). The
// 64-step chain runs redundantly in all 4 waves, but ON SALU: w is pinned
// scalar via readfirstlane, D words come from readlane (SGPR dst), so each
// step is s_and(SCC)+s_andn2+s_cselect (~4cy) instead of dependent 64-bit
// VALU (~45cy). All-zero diag quarters skip their chain (uniform branch).
__global__ __launch_bounds__(256, 1) void k_nms(const u64* __restrict__ mask,
                                                u64* __restrict__ keep) {
    __shared__ u64 lbuf[2][64][64];   // 64 KB, double-buffered
    __shared__ u64 s_part[2][4];
    __shared__ u64 s_all[4][64];
    const int lane = threadIdx.x & 63;
    const int wv   = threadIdx.x >> 6;
    u64 remv = 0ULL;
    u64 dA, dB;

    // stage wave wv's 16 rows of block b (8 KB = 8 x 1KB loads)
    #define STAGE(b, PAR) do {                                                 \
        const char* s_ = (const char*)mask + (size_t)(b) * 32768 + wv * 8192   \
                         + ((lane >> 5) << 9) + ((lane & 31) << 4);            \
        _Pragma("unroll")                                                      \
        for (int j_ = 0; j_ < 8; ++j_)                                         \
            __builtin_amdgcn_global_load_lds(                                  \
                (const unsigned int*)(s_ + j_ * 1024),                         \
                (unsigned int*)&lbuf[PAR][wv * 16 + j_ * 2][0], 16, 0, 0);     \
    } while (0)

    // per-lane diag word: lane r holds word b of row b*64+r (asm: issue-pinned)
    #define DIAG(b, dreg) do {                                                 \
        const u64* p_ = mask + (((size_t)((b) * 64 + lane)) << 6) + (b);       \
        asm volatile("global_load_dwordx2 %0, %1, off" : "=&v"(dreg) : "v"(p_)); \
    } while (0)

    #define BLOCK(b, PAR, dcur) do {                                           \
        if ((b) < 63) { asm volatile("s_waitcnt vmcnt(9)" ::: "memory"); }     \
        else          { asm volatile("s_waitcnt vmcnt(0)" ::: "memory"); }     \
        __builtin_amdgcn_sched_barrier(0);                                     \
        __builtin_amdgcn_s_barrier();                                          \
        __builtin_amdgcn_sched_barrier(0);                                     \
        u64 p0 = s_part[PAR][0], p1 = s_part[PAR][1];                          \
        u64 p2 = s_part[PAR][2], p3 = s_part[PAR][3];                          \
        u64 R[16];                                                             \
        _Pragma("unroll")                                                      \
        for (int j_ = 0; j_ < 16; ++j_) R[j_] = lbuf[PAR][wv * 16 + j_][lane]; \
        asm volatile("s_waitcnt lgkmcnt(0)" ::: "memory");                     \
        __builtin_amdgcn_sched_barrier(0);                                     \
        if ((b) < 62) STAGE((b) + 2, PAR);                                     \
        u64 w = ~readfirstlane64(p0 | p1 | p2 | p3);   /* SGPR-pinned */       \
        _Pragma("unroll")                                                      \
        for (int q_ = 0; q_ < 4; ++q_) {                                       \
            u64 D[16]; u64 acc_ = 0ULL;                                        \
            _Pragma("unroll")                                                  \
            for (int j_ = 0; j_ < 16; ++j_) {                                  \
                D[j_] = readlane64(dcur, q_ * 16 + j_);                        \
                acc_ |= D[j_];                                                 \
            }                                                                  \
            if (acc_) {                                                        \
                _Pragma("unroll")                                              \
                for (int j_ = 0; j_ < 16; ++j_) {                              \
                    u64 t_ = w & ~D[j_];                                       \
                    w = (w & (1ULL << (q_ * 16 + j_))) ? t_ : w;               \
                }                                                              \
            }                                                                  \
        }                                                                      \
        _Pragma("unroll")                                                      \
        for (int j_ = 0; j_ < 16; ++j_) {                                      \
            u64 m_ = (u64)0 - ((w >> (wv * 16 + j_)) & 1ULL);                  \
            remv |= m_ & R[j_];                                                \
        }                                                                      \
        if ((b) < 63) {                                                        \
            u64 pub = readlane64(remv, (b) + 1);                               \
            if (lane == 0) s_part[PAR ^ 1][wv] = pub;                          \
        }                                                                      \
        if ((b) < 62) DIAG((b) + 2, dcur);                                     \
        asm volatile("s_waitcnt lgkmcnt(0)" ::: "memory");                     \
        __builtin_amdgcn_sched_barrier(0);                                     \
    } while (0)

    // prologue: zero block-0 publish slot; blocks 0 and 1 fully in flight
    if (lane == 0) s_part[0][wv] = 0ULL;
    asm volatile("s_waitcnt lgkmcnt(0)" ::: "memory");
    STAGE(0, 0); DIAG(0, dA);
    STAGE(1, 1); DIAG(1, dB);

    for (int bb = 0; bb < 32; ++bb) {
        int b = bb * 2;
        BLOCK(b,     0, dA);
        BLOCK(b + 1, 1, dB);
    }
    #undef STAGE
    #undef DIAG
    #undef BLOCK

    s_all[wv][lane] = remv;
    __syncthreads();
    if (wv == 0)
        keep[lane] = ~(s_all[0][lane] | s_all[1][lane] | s_all[2][lane] | s_all[3][lane]);
}

// write [K,5] output
__global__ void k_out(const float4* __restrict__ tbox, const float* __restrict__ tsc,
                      const u64* __restrict__ keep, float* __restrict__ out) {
    int j = blockIdx.x * blockDim.x + threadIdx.x;
    if (j >= K_TOP) return;
    bool kp = (keep[j >> 6] >> (j & 63)) & 1ULL;
    float4 b = tbox[j];
    float sc = tsc[j];
    float* o = out + (size_t)j * 5;
    o[0] = kp ? b.x : 0.0f;
    o[1] = kp ? b.y : 0.0f;
    o[2] = kp ? b.z : 0.0f;
    o[3] = kp ? b.w : 0.0f;
    o[4] = kp ? sc  : 0.0f;
}

extern "C" void kernel_launch(void* const* d_in, const int* in_sizes, int n_in,
                              void* d_out, int out_size, void* d_ws, size_t ws_size,
                              hipStream_t stream) {
    if (ws_size < WS_NEED) return;  // fail loudly (output stays poisoned)
    const float* scores  = (const float*)d_in[0];
    const float* anchors = (const float*)d_in[1];
    const float* deltas  = (const float*)d_in[2];
    int n = in_sizes[0];

    char* ws = (char*)d_ws;
    unsigned* hist1 = (unsigned*)(ws + HIST1_OFF);
    unsigned* hist2 = (unsigned*)(ws + HIST2_OFF);
    unsigned* scal  = (unsigned*)(ws + SCAL_OFF);
    u64* cand       = (u64*)(ws + CAND_OFF);
    float4* tbox    = (float4*)(ws + TBOX_OFF);
    float* tsc      = (float*)(ws + TSC_OFF);
    u64* mask       = (u64*)(ws + MASK_OFF);
    u64* keep       = (u64*)(ws + KEEP_OFF);

    hipMemsetAsync(ws, 0, SCAL_OFF + 64, stream);  // hist1 + hist2 + scalars

    k_hist1<<<256, 256, 0, stream>>>(scores, hist1, n);
    k_select<<<1, 1024, 0, stream>>>(hist1, scal, 0);
    k_hist2<<<256, 256, 0, stream>>>(scores, scal, hist2, n);
    k_select<<<1, 1024, 0, stream>>>(hist2, scal, 1);
    k_compact<<<256, 256, 0, stream>>>(scores, scal, cand, &scal[5], n);
    k_rank_gather<<<CAP / 256, 256, 0, stream>>>(scores, anchors, deltas, cand, scal, tbox, tsc);
    k_mask<<<dim3(64, 64), 64, 0, stream>>>(tbox, mask);
    k_nms<<<1, 256, 0, stream>>>(mask, keep);
    k_out<<<16, 256, 0, stream>>>(tbox, tsc, keep, (float*)d_out);
}

// Round 11
// 170.621 us; speedup vs baseline: 1.6663x; 1.2669x over previous
//
#include <hip/hip_runtime.h>
#include <stdint.h>

#define K_TOP 4096
#define CAP 8192            // candidate buffer (pow2, >= K_TOP + ties margin)

// ---- workspace layout (bytes) ----
static constexpr size_t HIST1_OFF = 0;                                   // 4096 u32 = 16 KB
static constexpr size_t HIST2_OFF = 16384;                               // 4096 u32 = 16 KB
static constexpr size_t SCAL_OFF  = 32768;                               // 64 B scalars
static constexpr size_t CAND_OFF  = 32832;                               // CAP u64 = 64 KB
static constexpr size_t TBOX_OFF  = CAND_OFF + (size_t)CAP * 8;          // K float4 = 64 KB
static constexpr size_t TSC_OFF   = TBOX_OFF + (size_t)K_TOP * 16;       // K float = 16 KB
static constexpr size_t MASK_OFF  = TSC_OFF + (size_t)K_TOP * 4;         // K*64 u64 = 2 MB
static constexpr size_t KEEP_OFF  = MASK_OFF + (size_t)K_TOP * 64 * 8;   // 64 u64
static constexpr size_t DNZ_OFF   = KEEP_OFF + 512;                      // 64 u64 diag-nonzero bitmap
static constexpr size_t WS_NEED   = DNZ_OFF + 512;

// scal slots: [0]=B1 [1]=A1(count above B1) [4]=T24 threshold [5]=compact counter

typedef unsigned long long u64;

__device__ __forceinline__ unsigned ord_of(float s) {
    unsigned u = __float_as_uint(s);
    return (u & 0x80000000u) ? ~u : (u | 0x80000000u);
}

__device__ __forceinline__ u64 readlane64(u64 v, int l) {
    unsigned lo = (unsigned)__builtin_amdgcn_readlane((int)(unsigned)v, l);
    unsigned hi = (unsigned)__builtin_amdgcn_readlane((int)(v >> 32), l);
    return ((u64)hi << 32) | lo;
}

__device__ __forceinline__ u64 readfirstlane64(u64 v) {
    unsigned lo = (unsigned)__builtin_amdgcn_readfirstlane((int)(unsigned)v);
    unsigned hi = (unsigned)__builtin_amdgcn_readfirstlane((int)(v >> 32));
    return ((u64)hi << 32) | lo;
}

// P1: 12-bit histogram (bits 31..20 of ordered score), float4 loads, LDS-privatized
__global__ void k_hist1(const float* __restrict__ scores, unsigned* __restrict__ hist, int n) {
    __shared__ unsigned h[4096];
    for (int j = threadIdx.x; j < 4096; j += 256) h[j] = 0;
    __syncthreads();
    int gid = blockIdx.x * blockDim.x + threadIdx.x;
    int stride = gridDim.x * blockDim.x;
    int n4 = n >> 2;
    const float4* s4 = (const float4*)scores;
    for (int i = gid; i < n4; i += stride) {
        float4 v = s4[i];
        atomicAdd(&h[ord_of(v.x) >> 20], 1u);
        atomicAdd(&h[ord_of(v.y) >> 20], 1u);
        atomicAdd(&h[ord_of(v.z) >> 20], 1u);
        atomicAdd(&h[ord_of(v.w) >> 20], 1u);
    }
    for (int t = (n4 << 2) + gid; t < n; t += stride)
        atomicAdd(&h[ord_of(scores[t]) >> 20], 1u);
    __syncthreads();
    for (int j = threadIdx.x; j < 4096; j += 256) {
        unsigned v = h[j];
        if (v) atomicAdd(&hist[j], v);
    }
}

// P2: 12-bit histogram of bits 19..8 among elements whose top-12 == B1
__global__ void k_hist2(const float* __restrict__ scores, const unsigned* __restrict__ scal,
                        unsigned* __restrict__ hist, int n) {
    __shared__ unsigned h[4096];
    for (int j = threadIdx.x; j < 4096; j += 256) h[j] = 0;
    __syncthreads();
    unsigned B1 = scal[0];
    int gid = blockIdx.x * blockDim.x + threadIdx.x;
    int stride = gridDim.x * blockDim.x;
    int n4 = n >> 2;
    const float4* s4 = (const float4*)scores;
    for (int i = gid; i < n4; i += stride) {
        float4 v = s4[i];
        unsigned o0 = ord_of(v.x), o1 = ord_of(v.y), o2 = ord_of(v.z), o3 = ord_of(v.w);
        if ((o0 >> 20) == B1) atomicAdd(&h[(o0 >> 8) & 4095u], 1u);
        if ((o1 >> 20) == B1) atomicAdd(&h[(o1 >> 8) & 4095u], 1u);
        if ((o2 >> 20) == B1) atomicAdd(&h[(o2 >> 8) & 4095u], 1u);
        if ((o3 >> 20) == B1) atomicAdd(&h[(o3 >> 8) & 4095u], 1u);
    }
    for (int t = (n4 << 2) + gid; t < n; t += stride) {
        unsigned o = ord_of(scores[t]);
        if ((o >> 20) == B1) atomicAdd(&h[(o >> 8) & 4095u], 1u);
    }
    __syncthreads();
    for (int j = threadIdx.x; j < 4096; j += 256) {
        unsigned v = h[j];
        if (v) atomicAdd(&hist[j], v);
    }
}

// select threshold bin from a 4096-bin histogram via suffix scan
__global__ __launch_bounds__(1024) void k_select(const unsigned* __restrict__ hist,
                                                 unsigned* __restrict__ scal, int pass) {
    __shared__ unsigned buf[1024];
    int t = threadIdx.x;
    unsigned c0 = hist[t * 4 + 0], c1 = hist[t * 4 + 1];
    unsigned c2 = hist[t * 4 + 2], c3 = hist[t * 4 + 3];
    unsigned mysum = c0 + c1 + c2 + c3;
    buf[t] = mysum;
    __syncthreads();
    for (int off = 1; off < 1024; off <<= 1) {
        unsigned v = buf[t] + ((t + off < 1024) ? buf[t + off] : 0u);
        __syncthreads();
        buf[t] = v;
        __syncthreads();
    }
    unsigned target = (pass == 0) ? (unsigned)K_TOP : ((unsigned)K_TOP - scal[1]);
    unsigned sfx = buf[t];
    unsigned nxt = (t < 1023) ? buf[t + 1] : 0u;
    if (sfx >= target && nxt < target) {
        unsigned above = nxt;  // count in bins strictly above this 4-bin group
        unsigned b;
        if (above + c3 >= target)                { b = t * 4 + 3; }
        else if (above + c3 + c2 >= target)      { above += c3;           b = t * 4 + 2; }
        else if (above + c3 + c2 + c1 >= target) { above += c3 + c2;      b = t * 4 + 1; }
        else                                     { above += c3 + c2 + c1; b = t * 4 + 0; }
        if (pass == 0) { scal[0] = b; scal[1] = above; }
        else           { scal[4] = (scal[0] << 12) | b; }
    }
}

// compact all elements with 24-bit prefix >= T24, block-aggregated, float4 loads
__global__ __launch_bounds__(256) void k_compact(const float* __restrict__ scores,
                                                 const unsigned* __restrict__ scal,
                                                 u64* __restrict__ cand,
                                                 unsigned* __restrict__ counter, int n) {
    __shared__ unsigned lcount, lbase;
    __shared__ u64 lbuf[4096];
    if (threadIdx.x == 0) lcount = 0;
    __syncthreads();
    unsigned T = scal[4];
    int gid = blockIdx.x * blockDim.x + threadIdx.x;
    int stride = gridDim.x * blockDim.x;
    int n4 = n >> 2;
    const float4* s4 = (const float4*)scores;
    for (int i = gid; i < n4; i += stride) {
        float4 v = s4[i];
        unsigned o0 = ord_of(v.x), o1 = ord_of(v.y), o2 = ord_of(v.z), o3 = ord_of(v.w);
        int base = i << 2;
        if ((o0 >> 8) >= T) lbuf[atomicAdd(&lcount, 1u)] = ((u64)o0 << 32) | (unsigned)(~(base + 0));
        if ((o1 >> 8) >= T) lbuf[atomicAdd(&lcount, 1u)] = ((u64)o1 << 32) | (unsigned)(~(base + 1));
        if ((o2 >> 8) >= T) lbuf[atomicAdd(&lcount, 1u)] = ((u64)o2 << 32) | (unsigned)(~(base + 2));
        if ((o3 >> 8) >= T) lbuf[atomicAdd(&lcount, 1u)] = ((u64)o3 << 32) | (unsigned)(~(base + 3));
    }
    for (int t = (n4 << 2) + gid; t < n; t += stride) {
        unsigned o = ord_of(scores[t]);
        if ((o >> 8) >= T) lbuf[atomicAdd(&lcount, 1u)] = ((u64)o << 32) | (unsigned)(~t);
    }
    __syncthreads();
    if (threadIdx.x == 0) lbase = atomicAdd(counter, lcount);
    __syncthreads();
    for (unsigned j = threadIdx.x; j < lcount; j += 256) {
        unsigned p = lbase + j;
        if (p < CAP) cand[p] = lbuf[j];
    }
}

__device__ __forceinline__ float4 decode_clip(float4 a, float4 d) {
#pragma clang fp contract(off)
    const float BBOX_CLIP = (float)4.135166556742356;  // log(1000/16)
    float w  = a.z - a.x;
    float h  = a.w - a.y;
    float cx = a.x + 0.5f * w;
    float cy = a.y + 0.5f * h;
    float dx = d.x / 10.0f;
    float dy = d.y / 10.0f;
    float dw = fminf(d.z / 5.0f, BBOX_CLIP);
    float dh = fminf(d.w / 5.0f, BBOX_CLIP);
    float pcx = dx * w + cx;
    float pcy = dy * h + cy;
    float pw = (float)exp((double)dw) * w;
    float ph = (float)exp((double)dh) * h;
    float x1 = pcx - 0.5f * pw;
    float y1 = pcy - 0.5f * ph;
    float x2 = pcx + 0.5f * pw;
    float y2 = pcy + 0.5f * ph;
    x1 = fminf(fmaxf(x1, 0.0f), 1333.0f);
    y1 = fminf(fmaxf(y1, 0.0f), 800.0f);
    x2 = fminf(fmaxf(x2, 0.0f), 1333.0f);
    y2 = fminf(fmaxf(y2, 0.0f), 800.0f);
    return make_float4(x1, y1, x2, y2);
}

// rank-by-counting over candidates; decode straight into rank slot.
__global__ __launch_bounds__(256) void k_rank_gather(
        const float* __restrict__ scores, const float* __restrict__ anchors,
        const float* __restrict__ deltas, const u64* __restrict__ cand,
        const unsigned* __restrict__ scal, float4* __restrict__ tbox, float* __restrict__ tsc) {
    __shared__ u64 chunk[256];
    int t = threadIdx.x;
    int j = blockIdx.x * 256 + t;
    unsigned M = scal[5];
    if (M > CAP) M = CAP;
    u64 mykey = (j < (int)M) ? cand[j] : 0ULL;
    unsigned rank = 0;
    for (unsigned base = 0; base < M; base += 256) {
        unsigned idx = base + t;
        chunk[t] = (idx < M) ? cand[idx] : 0ULL;  // pad 0 < any valid key
        __syncthreads();
#pragma unroll 8
        for (int c = 0; c < 256; ++c) rank += (chunk[c] > mykey);
        __syncthreads();
    }
    if (j < (int)M && rank < K_TOP) {
        unsigned idx = ~(unsigned)mykey;
        float4 a = ((const float4*)anchors)[idx];
        float4 d = ((const float4*)deltas)[idx];
        tbox[rank] = decode_clip(a, d);
        tsc[rank]  = scores[idx];
    }
}

// suppression masks. Upper-triangle blocks computed; lower-triangle words
// ZERO-WRITTEN. Diagonal blocks (w==r) additionally publish a nonzero-row
// ballot to diagNZ[r] (bit t set iff row r*64+t's diag word != 0).
__global__ void k_mask(const float4* __restrict__ tbox, u64* __restrict__ mask,
                       u64* __restrict__ diagNZ) {
#pragma clang fp contract(off)
    int w = blockIdx.x;  // column word (64 cols)
    int r = blockIdx.y;  // row block
    int t = threadIdx.x;
    int i = r * 64 + t;
    if (w < r) { mask[(size_t)i * 64 + w] = 0ULL; return; }
    __shared__ float4 cb[64];
    __shared__ float  ca[64];
    float4 b = tbox[w * 64 + t];
    cb[t] = b;
    ca[t] = (b.z - b.x) * (b.w - b.y);
    __syncthreads();
    float4 bi = tbox[i];
    float ai = (bi.z - bi.x) * (bi.w - bi.y);
    u64 bits = 0ULL;
    for (int c = 0; c < 64; ++c) {
        int j = w * 64 + c;
        if (j > i) {
            float4 bj = cb[c];
            float ltx = fmaxf(bi.x, bj.x);
            float lty = fmaxf(bi.y, bj.y);
            float rbx = fminf(bi.z, bj.z);
            float rby = fminf(bi.w, bj.w);
            float ww = fmaxf(rbx - ltx, 0.0f);
            float hh = fmaxf(rby - lty, 0.0f);
            float inter = ww * hh;
            float denom = ((ai + ca[c]) - inter) + 1e-9f;
            float iou = inter / denom;
            if (iou > 0.7f) bits |= (1ULL << c);
        }
    }
    mask[(size_t)i * 64 + w] = bits;
    if (w == r) {
        u64 nz = __ballot(bits != 0ULL);
        if (t == 0) diagNZ[r] = nz;
    }
}

// 4-wave greedy NMS (256 threads). lane l owns column word l; wave v owns
// rows v*16..+15 of each block. Sparsity-gated chain: diagNZ marks rows with
// nonzero diagonal words; if the block's word is 0 (common for score-sorted
// random boxes), the 64-step chain and its 128-readlane extraction are
// SKIPPED entirely. Nonzero case: sparse ascending-bit extraction from the
// prefetched diag register. Staging/counted-vmcnt discipline from R10.
__global__ __launch_bounds__(256, 1) void k_nms(const u64* __restrict__ mask,
                                                const u64* __restrict__ diagNZ,
                                                u64* __restrict__ keep) {
    __shared__ u64 lbuf[2][64][64];   // 64 KB, double-buffered
    __shared__ u64 s_part[2][4];
    __shared__ u64 s_all[4][64];
    const int lane = threadIdx.x & 63;
    const int wv   = threadIdx.x >> 6;
    u64 remv = 0ULL;
    u64 dA, dB, dnzreg;

    // preload diagNZ[lane] — oldest VMEM op, retired by the first vmcnt(9)
    {
        const u64* p_ = diagNZ + lane;
        asm volatile("global_load_dwordx2 %0, %1, off" : "=&v"(dnzreg) : "v"(p_));
    }

    // stage wave wv's 16 rows of block b (8 KB = 8 x 1KB loads)
    #define STAGE(b, PAR) do {                                                 \
        const char* s_ = (const char*)mask + (size_t)(b) * 32768 + wv * 8192   \
                         + ((lane >> 5) << 9) + ((lane & 31) << 4);            \
        _Pragma("unroll")                                                      \
        for (int j_ = 0; j_ < 8; ++j_)                                         \
            __builtin_amdgcn_global_load_lds(                                  \
                (const unsigned int*)(s_ + j_ * 1024),                         \
                (unsigned int*)&lbuf[PAR][wv * 16 + j_ * 2][0], 16, 0, 0);     \
    } while (0)

    // per-lane diag word: lane r holds word b of row b*64+r (asm: issue-pinned)
    #define DIAG(b, dreg) do {                                                 \
        const u64* p_ = mask + (((size_t)((b) * 64 + lane)) << 6) + (b);       \
        asm volatile("global_load_dwordx2 %0, %1, off" : "=&v"(dreg) : "v"(p_)); \
    } while (0)

    #define BLOCK(b, PAR, dcur) do {                                           \
        if ((b) < 63) { asm volatile("s_waitcnt vmcnt(9)" ::: "memory"); }     \
        else          { asm volatile("s_waitcnt vmcnt(0)" ::: "memory"); }     \
        __builtin_amdgcn_sched_barrier(0);                                     \
        __builtin_amdgcn_s_barrier();                                          \
        __builtin_amdgcn_sched_barrier(0);                                     \
        u64 R[16];                                                             \
        _Pragma("unroll")                                                      \
        for (int j_ = 0; j_ < 16; ++j_) R[j_] = lbuf[PAR][wv * 16 + j_][lane]; \
        u64 p0 = s_part[PAR][0], p1 = s_part[PAR][1];                          \
        u64 p2 = s_part[PAR][2], p3 = s_part[PAR][3];                          \
        asm volatile("s_waitcnt lgkmcnt(0)" ::: "memory");                     \
        __builtin_amdgcn_sched_barrier(0);                                     \
        if ((b) < 62) STAGE((b) + 2, PAR);                                     \
        u64 w = ~readfirstlane64(p0 | p1 | p2 | p3);   /* SGPR-pinned */       \
        u64 dz = readlane64(dnzreg, (b));                                      \
        if (dz) {                                                              \
            u64 rem_ = dz;                                                     \
            while (rem_) {                                                     \
                int j_ = __builtin_ctzll(rem_);                                \
                rem_ &= rem_ - 1;                                              \
                if ((w >> j_) & 1ULL) w &= ~readlane64(dcur, j_);              \
            }                                                                  \
        }                                                                      \
        _Pragma("unroll")                                                      \
        for (int j_ = 0; j_ < 16; ++j_) {                                      \
            u64 m_ = (u64)0 - ((w >> (wv * 16 + j_)) & 1ULL);                  \
            remv |= m_ & R[j_];                                                \
        }                                                                      \
        if ((b) < 63) {                                                        \
            u64 pub = readlane64(remv, (b) + 1);                               \
            if (lane == 0) s_part[PAR ^ 1][wv] = pub;                          \
        }                                                                      \
        if ((b) < 62) DIAG((b) + 2, dcur);                                     \
        asm volatile("s_waitcnt lgkmcnt(0)" ::: "memory");                     \
        __builtin_amdgcn_sched_barrier(0);                                     \
    } while (0)

    // prologue: zero block-0 publish slot; blocks 0 and 1 fully in flight
    if (lane == 0) s_part[0][wv] = 0ULL;
    asm volatile("s_waitcnt lgkmcnt(0)" ::: "memory");
    STAGE(0, 0); DIAG(0, dA);
    STAGE(1, 1); DIAG(1, dB);

    for (int bb = 0; bb < 32; ++bb) {
        int b = bb * 2;
        BLOCK(b,     0, dA);
        BLOCK(b + 1, 1, dB);
    }
    #undef STAGE
    #undef DIAG
    #undef BLOCK

    s_all[wv][lane] = remv;
    __syncthreads();
    if (wv == 0)
        keep[lane] = ~(s_all[0][lane] | s_all[1][lane] | s_all[2][lane] | s_all[3][lane]);
}

// write [K,5] output
__global__ void k_out(const float4* __restrict__ tbox, const float* __restrict__ tsc,
                      const u64* __restrict__ keep, float* __restrict__ out) {
    int j = blockIdx.x * blockDim.x + threadIdx.x;
    if (j >= K_TOP) return;
    bool kp = (keep[j >> 6] >> (j & 63)) & 1ULL;
    float4 b = tbox[j];
    float sc = tsc[j];
    float* o = out + (size_t)j * 5;
    o[0] = kp ? b.x : 0.0f;
    o[1] = kp ? b.y : 0.0f;
    o[2] = kp ? b.z : 0.0f;
    o[3] = kp ? b.w : 0.0f;
    o[4] = kp ? sc  : 0.0f;
}

extern "C" void kernel_launch(void* const* d_in, const int* in_sizes, int n_in,
                              void* d_out, int out_size, void* d_ws, size_t ws_size,
                              hipStream_t stream) {
    if (ws_size < WS_NEED) return;  // fail loudly (output stays poisoned)
    const float* scores  = (const float*)d_in[0];
    const float* anchors = (const float*)d_in[1];
    const float* deltas  = (const float*)d_in[2];
    int n = in_sizes[0];

    char* ws = (char*)d_ws;
    unsigned* hist1 = (unsigned*)(ws + HIST1_OFF);
    unsigned* hist2 = (unsigned*)(ws + HIST2_OFF);
    unsigned* scal  = (unsigned*)(ws + SCAL_OFF);
    u64* cand       = (u64*)(ws + CAND_OFF);
    float4* tbox    = (float4*)(ws + TBOX_OFF);
    float* tsc      = (float*)(ws + TSC_OFF);
    u64* mask       = (u64*)(ws + MASK_OFF);
    u64* keep       = (u64*)(ws + KEEP_OFF);
    u64* dnz        = (u64*)(ws + DNZ_OFF);

    hipMemsetAsync(ws, 0, SCAL_OFF + 64, stream);  // hist1 + hist2 + scalars

    k_hist1<<<256, 256, 0, stream>>>(scores, hist1, n);
    k_select<<<1, 1024, 0, stream>>>(hist1, scal, 0);
    k_hist2<<<256, 256, 0, stream>>>(scores, scal, hist2, n);
    k_select<<<1, 1024, 0, stream>>>(hist2, scal, 1);
    k_compact<<<256, 256, 0, stream>>>(scores, scal, cand, &scal[5], n);
    k_rank_gather<<<CAP / 256, 256, 0, stream>>>(scores, anchors, deltas, cand, scal, tbox, tsc);
    k_mask<<<dim3(64, 64), 64, 0, stream>>>(tbox, mask, dnz);
    k_nms<<<1, 256, 0, stream>>>(mask, dnz, keep);
    k_out<<<16, 256, 0, stream>>>(tbox, tsc, keep, (float*)d_out);
}

// Round 12
// 117.328 us; speedup vs baseline: 2.4232x; 1.4542x over previous
//
#include <hip/hip_runtime.h>
#include <stdint.h>

#define K_TOP 4096
#define CAP 8192            // candidate buffer (pow2, >= K_TOP + ties margin)
#define NSEG 16
#define SEGLEN (CAP / NSEG) // 512

// ---- workspace layout (bytes) ----
static constexpr size_t HIST1_OFF = 0;                                   // 4096 u32 = 16 KB
static constexpr size_t HIST2_OFF = 16384;                               // 4096 u32 = 16 KB
static constexpr size_t SCAL_OFF  = 32768;                               // 64 B scalars
static constexpr size_t CAND_OFF  = 32832;                               // CAP u64 = 64 KB
static constexpr size_t TBOX_OFF  = CAND_OFF + (size_t)CAP * 8;          // K float4 = 64 KB
static constexpr size_t TSC_OFF   = TBOX_OFF + (size_t)K_TOP * 16;       // K float = 16 KB
static constexpr size_t MASK_OFF  = TSC_OFF + (size_t)K_TOP * 4;         // K*64 u64 = 2 MB
static constexpr size_t KEEP_OFF  = MASK_OFF + (size_t)K_TOP * 64 * 8;   // 64 u64
static constexpr size_t DNZ_OFF   = KEEP_OFF + 512;                      // 64 u64 diag-nonzero bitmap
static constexpr size_t PART_OFF  = DNZ_OFF + 512;                       // NSEG*CAP u32 = 512 KB
static constexpr size_t WS_NEED   = PART_OFF + (size_t)NSEG * CAP * 4;

// scal slots: [0]=B1 [1]=A1(count above B1) [4]=T24 threshold [5]=compact counter

typedef unsigned long long u64;

__device__ __forceinline__ unsigned ord_of(float s) {
    unsigned u = __float_as_uint(s);
    return (u & 0x80000000u) ? ~u : (u | 0x80000000u);
}

__device__ __forceinline__ u64 readlane64(u64 v, int l) {
    unsigned lo = (unsigned)__builtin_amdgcn_readlane((int)(unsigned)v, l);
    unsigned hi = (unsigned)__builtin_amdgcn_readlane((int)(v >> 32), l);
    return ((u64)hi << 32) | lo;
}

__device__ __forceinline__ u64 readfirstlane64(u64 v) {
    unsigned lo = (unsigned)__builtin_amdgcn_readfirstlane((int)(unsigned)v);
    unsigned hi = (unsigned)__builtin_amdgcn_readfirstlane((int)(v >> 32));
    return ((u64)hi << 32) | lo;
}

// P1: 12-bit histogram (bits 31..20 of ordered score), float4 loads, LDS-privatized
__global__ void k_hist1(const float* __restrict__ scores, unsigned* __restrict__ hist, int n) {
    __shared__ unsigned h[4096];
    for (int j = threadIdx.x; j < 4096; j += 256) h[j] = 0;
    __syncthreads();
    int gid = blockIdx.x * blockDim.x + threadIdx.x;
    int stride = gridDim.x * blockDim.x;
    int n4 = n >> 2;
    const float4* s4 = (const float4*)scores;
    for (int i = gid; i < n4; i += stride) {
        float4 v = s4[i];
        atomicAdd(&h[ord_of(v.x) >> 20], 1u);
        atomicAdd(&h[ord_of(v.y) >> 20], 1u);
        atomicAdd(&h[ord_of(v.z) >> 20], 1u);
        atomicAdd(&h[ord_of(v.w) >> 20], 1u);
    }
    for (int t = (n4 << 2) + gid; t < n; t += stride)
        atomicAdd(&h[ord_of(scores[t]) >> 20], 1u);
    __syncthreads();
    for (int j = threadIdx.x; j < 4096; j += 256) {
        unsigned v = h[j];
        if (v) atomicAdd(&hist[j], v);
    }
}

// P2: 12-bit histogram of bits 19..8 among elements whose top-12 == B1
__global__ void k_hist2(const float* __restrict__ scores, const unsigned* __restrict__ scal,
                        unsigned* __restrict__ hist, int n) {
    __shared__ unsigned h[4096];
    for (int j = threadIdx.x; j < 4096; j += 256) h[j] = 0;
    __syncthreads();
    unsigned B1 = scal[0];
    int gid = blockIdx.x * blockDim.x + threadIdx.x;
    int stride = gridDim.x * blockDim.x;
    int n4 = n >> 2;
    const float4* s4 = (const float4*)scores;
    for (int i = gid; i < n4; i += stride) {
        float4 v = s4[i];
        unsigned o0 = ord_of(v.x), o1 = ord_of(v.y), o2 = ord_of(v.z), o3 = ord_of(v.w);
        if ((o0 >> 20) == B1) atomicAdd(&h[(o0 >> 8) & 4095u], 1u);
        if ((o1 >> 20) == B1) atomicAdd(&h[(o1 >> 8) & 4095u], 1u);
        if ((o2 >> 20) == B1) atomicAdd(&h[(o2 >> 8) & 4095u], 1u);
        if ((o3 >> 20) == B1) atomicAdd(&h[(o3 >> 8) & 4095u], 1u);
    }
    for (int t = (n4 << 2) + gid; t < n; t += stride) {
        unsigned o = ord_of(scores[t]);
        if ((o >> 20) == B1) atomicAdd(&h[(o >> 8) & 4095u], 1u);
    }
    __syncthreads();
    for (int j = threadIdx.x; j < 4096; j += 256) {
        unsigned v = h[j];
        if (v) atomicAdd(&hist[j], v);
    }
}

// select threshold bin from a 4096-bin histogram via suffix scan
__global__ __launch_bounds__(1024) void k_select(const unsigned* __restrict__ hist,
                                                 unsigned* __restrict__ scal, int pass) {
    __shared__ unsigned buf[1024];
    int t = threadIdx.x;
    unsigned c0 = hist[t * 4 + 0], c1 = hist[t * 4 + 1];
    unsigned c2 = hist[t * 4 + 2], c3 = hist[t * 4 + 3];
    unsigned mysum = c0 + c1 + c2 + c3;
    buf[t] = mysum;
    __syncthreads();
    for (int off = 1; off < 1024; off <<= 1) {
        unsigned v = buf[t] + ((t + off < 1024) ? buf[t + off] : 0u);
        __syncthreads();
        buf[t] = v;
        __syncthreads();
    }
    unsigned target = (pass == 0) ? (unsigned)K_TOP : ((unsigned)K_TOP - scal[1]);
    unsigned sfx = buf[t];
    unsigned nxt = (t < 1023) ? buf[t + 1] : 0u;
    if (sfx >= target && nxt < target) {
        unsigned above = nxt;  // count in bins strictly above this 4-bin group
        unsigned b;
        if (above + c3 >= target)                { b = t * 4 + 3; }
        else if (above + c3 + c2 >= target)      { above += c3;           b = t * 4 + 2; }
        else if (above + c3 + c2 + c1 >= target) { above += c3 + c2;      b = t * 4 + 1; }
        else                                     { above += c3 + c2 + c1; b = t * 4 + 0; }
        if (pass == 0) { scal[0] = b; scal[1] = above; }
        else           { scal[4] = (scal[0] << 12) | b; }
    }
}

// compact all elements with 24-bit prefix >= T24, block-aggregated, float4 loads
__global__ __launch_bounds__(256) void k_compact(const float* __restrict__ scores,
                                                 const unsigned* __restrict__ scal,
                                                 u64* __restrict__ cand,
                                                 unsigned* __restrict__ counter, int n) {
    __shared__ unsigned lcount, lbase;
    __shared__ u64 lbuf[4096];
    if (threadIdx.x == 0) lcount = 0;
    __syncthreads();
    unsigned T = scal[4];
    int gid = blockIdx.x * blockDim.x + threadIdx.x;
    int stride = gridDim.x * blockDim.x;
    int n4 = n >> 2;
    const float4* s4 = (const float4*)scores;
    for (int i = gid; i < n4; i += stride) {
        float4 v = s4[i];
        unsigned o0 = ord_of(v.x), o1 = ord_of(v.y), o2 = ord_of(v.z), o3 = ord_of(v.w);
        int base = i << 2;
        if ((o0 >> 8) >= T) lbuf[atomicAdd(&lcount, 1u)] = ((u64)o0 << 32) | (unsigned)(~(base + 0));
        if ((o1 >> 8) >= T) lbuf[atomicAdd(&lcount, 1u)] = ((u64)o1 << 32) | (unsigned)(~(base + 1));
        if ((o2 >> 8) >= T) lbuf[atomicAdd(&lcount, 1u)] = ((u64)o2 << 32) | (unsigned)(~(base + 2));
        if ((o3 >> 8) >= T) lbuf[atomicAdd(&lcount, 1u)] = ((u64)o3 << 32) | (unsigned)(~(base + 3));
    }
    for (int t = (n4 << 2) + gid; t < n; t += stride) {
        unsigned o = ord_of(scores[t]);
        if ((o >> 8) >= T) lbuf[atomicAdd(&lcount, 1u)] = ((u64)o << 32) | (unsigned)(~t);
    }
    __syncthreads();
    if (threadIdx.x == 0) lbase = atomicAdd(counter, lcount);
    __syncthreads();
    for (unsigned j = threadIdx.x; j < lcount; j += 256) {
        unsigned p = lbase + j;
        if (p < CAP) cand[p] = lbuf[j];
    }
}

__device__ __forceinline__ float4 decode_clip(float4 a, float4 d) {
#pragma clang fp contract(off)
    const float BBOX_CLIP = (float)4.135166556742356;  // log(1000/16)
    float w  = a.z - a.x;
    float h  = a.w - a.y;
    float cx = a.x + 0.5f * w;
    float cy = a.y + 0.5f * h;
    float dx = d.x / 10.0f;
    float dy = d.y / 10.0f;
    float dw = fminf(d.z / 5.0f, BBOX_CLIP);
    float dh = fminf(d.w / 5.0f, BBOX_CLIP);
    float pcx = dx * w + cx;
    float pcy = dy * h + cy;
    float pw = (float)exp((double)dw) * w;
    float ph = (float)exp((double)dh) * h;
    float x1 = pcx - 0.5f * pw;
    float y1 = pcy - 0.5f * ph;
    float x2 = pcx + 0.5f * pw;
    float y2 = pcy + 0.5f * ph;
    x1 = fminf(fmaxf(x1, 0.0f), 1333.0f);
    y1 = fminf(fmaxf(y1, 0.0f), 800.0f);
    x2 = fminf(fmaxf(x2, 0.0f), 1333.0f);
    y2 = fminf(fmaxf(y2, 0.0f), 800.0f);
    return make_float4(x1, y1, x2, y2);
}

// partial rank counts: block (jb, sb) counts jb's 256 candidates against
// segment sb's 512 keys. Plain coalesced stores, no atomics.
__global__ __launch_bounds__(256) void k_rank(const u64* __restrict__ cand,
                                              const unsigned* __restrict__ scal,
                                              unsigned* __restrict__ part) {
    __shared__ u64 seg[SEGLEN];
    int t = threadIdx.x;
    int jb = blockIdx.x;   // candidate block 0..31
    int sb = blockIdx.y;   // segment 0..NSEG-1
    unsigned M = scal[5];
    if (M > CAP) M = CAP;
#pragma unroll
    for (int k = 0; k < SEGLEN / 256; ++k) {
        unsigned idx = sb * SEGLEN + k * 256 + t;
        seg[k * 256 + t] = (idx < M) ? cand[idx] : 0ULL;  // pad 0 < any valid key
    }
    __syncthreads();
    int j = jb * 256 + t;
    u64 mykey = (j < (int)M) ? cand[j] : 0ULL;
    unsigned cnt = 0;
#pragma unroll 8
    for (int c = 0; c < SEGLEN; ++c) cnt += (seg[c] > mykey);
    part[(size_t)sb * CAP + j] = cnt;
}

// sum partials -> final rank; decode straight into rank slot.
// keys unique -> ranks are a permutation; rank < K_TOP selects the top-K.
__global__ __launch_bounds__(256) void k_gather(
        const float* __restrict__ scores, const float* __restrict__ anchors,
        const float* __restrict__ deltas, const u64* __restrict__ cand,
        const unsigned* __restrict__ scal, const unsigned* __restrict__ part,
        float4* __restrict__ tbox, float* __restrict__ tsc) {
    int j = blockIdx.x * 256 + threadIdx.x;
    unsigned M = scal[5];
    if (M > CAP) M = CAP;
    if (j >= (int)M) return;
    unsigned rank = 0;
#pragma unroll
    for (int s = 0; s < NSEG; ++s) rank += part[(size_t)s * CAP + j];
    if (rank < K_TOP) {
        unsigned idx = ~(unsigned)cand[j];
        float4 a = ((const float4*)anchors)[idx];
        float4 d = ((const float4*)deltas)[idx];
        tbox[rank] = decode_clip(a, d);
        tsc[rank]  = scores[idx];
    }
}

// suppression masks. Upper-triangle blocks computed; lower-triangle words
// ZERO-WRITTEN. Diagonal blocks (w==r) additionally publish a nonzero-row
// ballot to diagNZ[r] (bit t set iff row r*64+t's diag word != 0).
__global__ void k_mask(const float4* __restrict__ tbox, u64* __restrict__ mask,
                       u64* __restrict__ diagNZ) {
#pragma clang fp contract(off)
    int w = blockIdx.x;  // column word (64 cols)
    int r = blockIdx.y;  // row block
    int t = threadIdx.x;
    int i = r * 64 + t;
    if (w < r) { mask[(size_t)i * 64 + w] = 0ULL; return; }
    __shared__ float4 cb[64];
    __shared__ float  ca[64];
    float4 b = tbox[w * 64 + t];
    cb[t] = b;
    ca[t] = (b.z - b.x) * (b.w - b.y);
    __syncthreads();
    float4 bi = tbox[i];
    float ai = (bi.z - bi.x) * (bi.w - bi.y);
    u64 bits = 0ULL;
    for (int c = 0; c < 64; ++c) {
        int j = w * 64 + c;
        if (j > i) {
            float4 bj = cb[c];
            float ltx = fmaxf(bi.x, bj.x);
            float lty = fmaxf(bi.y, bj.y);
            float rbx = fminf(bi.z, bj.z);
            float rby = fminf(bi.w, bj.w);
            float ww = fmaxf(rbx - ltx, 0.0f);
            float hh = fmaxf(rby - lty, 0.0f);
            float inter = ww * hh;
            float denom = ((ai + ca[c]) - inter) + 1e-9f;
            float iou = inter / denom;
            if (iou > 0.7f) bits |= (1ULL << c);
        }
    }
    mask[(size_t)i * 64 + w] = bits;
    if (w == r) {
        u64 nz = __ballot(bits != 0ULL);
        if (t == 0) diagNZ[r] = nz;
    }
}

// 4-wave greedy NMS (256 threads). lane l owns column word l; wave v owns
// rows v*16..+15 of each block. Sparsity-gated chain via diagNZ; counted
// vmcnt staging discipline (verified R10/R11).
__global__ __launch_bounds__(256, 1) void k_nms(const u64* __restrict__ mask,
                                                const u64* __restrict__ diagNZ,
                                                u64* __restrict__ keep) {
    __shared__ u64 lbuf[2][64][64];   // 64 KB, double-buffered
    __shared__ u64 s_part[2][4];
    __shared__ u64 s_all[4][64];
    const int lane = threadIdx.x & 63;
    const int wv   = threadIdx.x >> 6;
    u64 remv = 0ULL;
    u64 dA, dB, dnzreg;

    // preload diagNZ[lane] — oldest VMEM op, retired by the first vmcnt(9)
    {
        const u64* p_ = diagNZ + lane;
        asm volatile("global_load_dwordx2 %0, %1, off" : "=&v"(dnzreg) : "v"(p_));
    }

    // stage wave wv's 16 rows of block b (8 KB = 8 x 1KB loads)
    #define STAGE(b, PAR) do {                                                 \
        const char* s_ = (const char*)mask + (size_t)(b) * 32768 + wv * 8192   \
                         + ((lane >> 5) << 9) + ((lane & 31) << 4);            \
        _Pragma("unroll")                                                      \
        for (int j_ = 0; j_ < 8; ++j_)                                         \
            __builtin_amdgcn_global_load_lds(                                  \
                (const unsigned int*)(s_ + j_ * 1024),                         \
                (unsigned int*)&lbuf[PAR][wv * 16 + j_ * 2][0], 16, 0, 0);     \
    } while (0)

    // per-lane diag word: lane r holds word b of row b*64+r (asm: issue-pinned)
    #define DIAG(b, dreg) do {                                                 \
        const u64* p_ = mask + (((size_t)((b) * 64 + lane)) << 6) + (b);       \
        asm volatile("global_load_dwordx2 %0, %1, off" : "=&v"(dreg) : "v"(p_)); \
    } while (0)

    #define BLOCK(b, PAR, dcur) do {                                           \
        if ((b) < 63) { asm volatile("s_waitcnt vmcnt(9)" ::: "memory"); }     \
        else          { asm volatile("s_waitcnt vmcnt(0)" ::: "memory"); }     \
        __builtin_amdgcn_sched_barrier(0);                                     \
        __builtin_amdgcn_s_barrier();                                          \
        __builtin_amdgcn_sched_barrier(0);                                     \
        u64 R[16];                                                             \
        _Pragma("unroll")                                                      \
        for (int j_ = 0; j_ < 16; ++j_) R[j_] = lbuf[PAR][wv * 16 + j_][lane]; \
        u64 p0 = s_part[PAR][0], p1 = s_part[PAR][1];                          \
        u64 p2 = s_part[PAR][2], p3 = s_part[PAR][3];                          \
        asm volatile("s_waitcnt lgkmcnt(0)" ::: "memory");                     \
        __builtin_amdgcn_sched_barrier(0);                                     \
        if ((b) < 62) STAGE((b) + 2, PAR);                                     \
        u64 w = ~readfirstlane64(p0 | p1 | p2 | p3);   /* SGPR-pinned */       \
        u64 dz = readlane64(dnzreg, (b));                                      \
        if (dz) {                                                              \
            u64 rem_ = dz;                                                     \
            while (rem_) {                                                     \
                int j_ = __builtin_ctzll(rem_);                                \
                rem_ &= rem_ - 1;                                              \
                if ((w >> j_) & 1ULL) w &= ~readlane64(dcur, j_);              \
            }                                                                  \
        }                                                                      \
        _Pragma("unroll")                                                      \
        for (int j_ = 0; j_ < 16; ++j_) {                                      \
            u64 m_ = (u64)0 - ((w >> (wv * 16 + j_)) & 1ULL);                  \
            remv |= m_ & R[j_];                                                \
        }                                                                      \
        if ((b) < 63) {                                                        \
            u64 pub = readlane64(remv, (b) + 1);                               \
            if (lane == 0) s_part[PAR ^ 1][wv] = pub;                          \
        }                                                                      \
        if ((b) < 62) DIAG((b) + 2, dcur);                                     \
        asm volatile("s_waitcnt lgkmcnt(0)" ::: "memory");                     \
        __builtin_amdgcn_sched_barrier(0);                                     \
    } while (0)

    // prologue: zero block-0 publish slot; blocks 0 and 1 fully in flight
    if (lane == 0) s_part[0][wv] = 0ULL;
    asm volatile("s_waitcnt lgkmcnt(0)" ::: "memory");
    STAGE(0, 0); DIAG(0, dA);
    STAGE(1, 1); DIAG(1, dB);

    for (int bb = 0; bb < 32; ++bb) {
        int b = bb * 2;
        BLOCK(b,     0, dA);
        BLOCK(b + 1, 1, dB);
    }
    #undef STAGE
    #undef DIAG
    #undef BLOCK

    s_all[wv][lane] = remv;
    __syncthreads();
    if (wv == 0)
        keep[lane] = ~(s_all[0][lane] | s_all[1][lane] | s_all[2][lane] | s_all[3][lane]);
}

// write [K,5] output
__global__ void k_out(const float4* __restrict__ tbox, const float* __restrict__ tsc,
                      const u64* __restrict__ keep, float* __restrict__ out) {
    int j = blockIdx.x * blockDim.x + threadIdx.x;
    if (j >= K_TOP) return;
    bool kp = (keep[j >> 6] >> (j & 63)) & 1ULL;
    float4 b = tbox[j];
    float sc = tsc[j];
    float* o = out + (size_t)j * 5;
    o[0] = kp ? b.x : 0.0f;
    o[1] = kp ? b.y : 0.0f;
    o[2] = kp ? b.z : 0.0f;
    o[3] = kp ? b.w : 0.0f;
    o[4] = kp ? sc  : 0.0f;
}

extern "C" void kernel_launch(void* const* d_in, const int* in_sizes, int n_in,
                              void* d_out, int out_size, void* d_ws, size_t ws_size,
                              hipStream_t stream) {
    if (ws_size < WS_NEED) return;  // fail loudly (output stays poisoned)
    const float* scores  = (const float*)d_in[0];
    const float* anchors = (const float*)d_in[1];
    const float* deltas  = (const float*)d_in[2];
    int n = in_sizes[0];

    char* ws = (char*)d_ws;
    unsigned* hist1 = (unsigned*)(ws + HIST1_OFF);
    unsigned* hist2 = (unsigned*)(ws + HIST2_OFF);
    unsigned* scal  = (unsigned*)(ws + SCAL_OFF);
    u64* cand       = (u64*)(ws + CAND_OFF);
    float4* tbox    = (float4*)(ws + TBOX_OFF);
    float* tsc      = (float*)(ws + TSC_OFF);
    u64* mask       = (u64*)(ws + MASK_OFF);
    u64* keep       = (u64*)(ws + KEEP_OFF);
    u64* dnz        = (u64*)(ws + DNZ_OFF);
    unsigned* part  = (unsigned*)(ws + PART_OFF);

    hipMemsetAsync(ws, 0, SCAL_OFF + 64, stream);  // hist1 + hist2 + scalars

    k_hist1<<<256, 256, 0, stream>>>(scores, hist1, n);
    k_select<<<1, 1024, 0, stream>>>(hist1, scal, 0);
    k_hist2<<<256, 256, 0, stream>>>(scores, scal, hist2, n);
    k_select<<<1, 1024, 0, stream>>>(hist2, scal, 1);
    k_compact<<<256, 256, 0, stream>>>(scores, scal, cand, &scal[5], n);
    k_rank<<<dim3(CAP / 256, NSEG), 256, 0, stream>>>(cand, scal, part);
    k_gather<<<CAP / 256, 256, 0, stream>>>(scores, anchors, deltas, cand, scal, part, tbox, tsc);
    k_mask<<<dim3(64, 64), 64, 0, stream>>>(tbox, mask, dnz);
    k_nms<<<1, 256, 0, stream>>>(mask, dnz, keep);
    k_out<<<16, 256, 0, stream>>>(tbox, tsc, keep, (float*)d_out);
}